// Round 3
// baseline (1056.022 us; speedup 1.0000x reference)
//
#include <hip/hip_runtime.h>
#include <hip/hip_bf16.h>
#include <cstdint>

// Problem constants (B,C,H,W fixed by setup_inputs)
constexpr int NB = 4;
constexpr int NC = 64;
constexpr int NH = 96;
constexpr int NW = 256;
constexpr int HWp = NH * NW;          // 24576 pixels per plane
constexpr float EPS = 1e-6f;

typedef __attribute__((ext_vector_type(8))) short short8;
typedef __attribute__((ext_vector_type(4))) short short4t;
typedef __attribute__((ext_vector_type(4))) float f32x4;

static __device__ __forceinline__ short f2bf(float f) {
    __hip_bfloat16 h = __float2bfloat16(f);
    return *reinterpret_cast<short*>(&h);
}

// ---------------------------------------------------------------------------
// LayerNorm2d over channels at each (b,h,w). Block = one (b,h) row, 256 thr.
// ---------------------------------------------------------------------------
__global__ __launch_bounds__(256) void k_ln(const float* __restrict__ x,
                                            const float* __restrict__ g,
                                            const float* __restrict__ bta,
                                            float* __restrict__ out) {
    int h = blockIdx.x, b = blockIdx.y, w = threadIdx.x;
    const float* xp = x + ((size_t)b * NC * NH + h) * NW + w;
    float v[64];
    float s = 0.f, sq = 0.f;
#pragma unroll
    for (int c = 0; c < 64; ++c) {
        float t = xp[(size_t)c * HWp];
        v[c] = t; s += t; sq += t * t;
    }
    float mu = s * (1.f / 64.f);
    float var = sq * (1.f / 64.f) - mu * mu;
    float rs = rsqrtf(var + EPS);
    float* op = out + ((size_t)b * NC * NH + h) * NW + w;
#pragma unroll
    for (int c = 0; c < 64; ++c) op[(size_t)c * HWp] = (v[c] - mu) * rs * g[c] + bta[c];
}

// ---------------------------------------------------------------------------
// Rectangle sums for the SKM global pool (D never materialized).
// T layout: [b][m][ci][9]
// ---------------------------------------------------------------------------
__global__ __launch_bounds__(256) void k_rect(const float* __restrict__ xln,
                                              float* __restrict__ T) {
    int bci = blockIdx.x;
    int b = bci >> 6, ci = bci & 63;
    int t = threadIdx.x, lane = t & 63, wv = t >> 6;
    __shared__ float rp[NH][9];
    const float* base = xln + (size_t)bci * HWp;
    for (int r = wv; r < NH; r += 4) {
        float4 vv = *(const float4*)(base + r * NW + lane * 4);
        float a = vv.x + vv.y, bb = vv.z + vv.w;
        float s4 = a + bb;
        float full = s4;
#pragma unroll
        for (int o = 32; o; o >>= 1) full += __shfl_xor(full, o, 64);
        float l0a = __shfl(a, 0, 64),  l0s = __shfl(s4, 0, 64);
        float l1a = __shfl(a, 1, 64),  l1s = __shfl(s4, 1, 64);
        float r63b = __shfl(bb, 63, 64), r63s = __shfl(s4, 63, 64);
        float r62b = __shfl(bb, 62, 64), r62s = __shfl(s4, 62, 64);
        if (lane == 0) {
            rp[r][0] = full;
            rp[r][1] = l0a;  rp[r][2] = l0s;  rp[r][3] = l0s + l1a;  rp[r][4] = l0s + l1s;
            rp[r][5] = r63b; rp[r][6] = r63s; rp[r][7] = r63s + r62b; rp[r][8] = r63s + r62s;
        }
    }
    __syncthreads();
    if (t < 36) {
        int m = t / 9, kh = (t % 9) / 3, kw = t % 3;
        int d = 2 * (m + 1);
        int r0 = (kh == 2) ? d : 0;
        int r1 = (kh == 0) ? NH - d : NH;
        float s = 0.f;
        for (int r = r0; r < r1; ++r) {
            float rowv = rp[r][0];
            if (kw == 0) rowv -= rp[r][5 + m];
            else if (kw == 2) rowv -= rp[r][1 + m];
            s += rowv;
        }
        T[(((b * 4 + m) * 64) + ci) * 9 + kh * 3 + kw] = s;
    }
}

// ---------------------------------------------------------------------------
// SKM selection MLP: Z -> S -> P -> softmax over C -> Sw, plus folded bias.
// ---------------------------------------------------------------------------
__global__ __launch_bounds__(256) void k_select(const float* __restrict__ T,
                                                const float* __restrict__ dw,
                                                const float* __restrict__ db,
                                                const float* __restrict__ c1w,
                                                const float* __restrict__ c1b,
                                                const float* __restrict__ pw,
                                                float* __restrict__ Sw,
                                                float* __restrict__ Qb) {
    int t = threadIdx.x;
    __shared__ float zs[256], ss[512], ps[1024], sw[1024];
    {
        int b = t >> 6, c = t & 63;
        float acc = 0.f, bias = 0.f;
        for (int m = 0; m < 4; ++m) {
            const float* wp = dw + (size_t)(m * 64 + c) * 576;
            const float* tp = T + (size_t)(b * 4 + m) * 576;
            float a2 = 0.f;
            for (int j = 0; j < 576; ++j) a2 += wp[j] * tp[j];
            acc += a2;
            bias += db[m * 64 + c];
        }
        zs[t] = acc * (1.f / (float)HWp) + bias;
    }
    __syncthreads();
    for (int i = t; i < 512; i += 256) {
        int b = i >> 7, j = i & 127;
        float s = c1b[j];
        const float* wrow = c1w + j * 64;
        const float* zb = zs + b * 64;
        for (int c = 0; c < 64; ++c) s += zb[c] * wrow[c];
        ss[i] = fmaxf(s, 0.f);
    }
    __syncthreads();
    for (int i = t; i < 1024; i += 256) {
        int b = i >> 8, rem = i & 255;
        float p = 0.f;
        const float* sb = ss + b * 128;
        for (int j = 0; j < 128; ++j) p += sb[j] * pw[j * 256 + rem];
        ps[i] = p;
    }
    __syncthreads();
    if (t < 16) {
        int b = t >> 2, m = t & 3;
        const float* pp = ps + b * 256 + m * 64;
        float mx = -1e30f;
        for (int c = 0; c < 64; ++c) mx = fmaxf(mx, pp[c]);
        float sum = 0.f;
        for (int c = 0; c < 64; ++c) sum += expf(pp[c] - mx);
        float inv = 1.f / sum;
        for (int c = 0; c < 64; ++c) sw[b * 256 + m * 64 + c] = expf(pp[c] - mx) * inv;
    }
    __syncthreads();
    {
        int b = t >> 6, c = t & 63;
        float qb = 0.f;
#pragma unroll
        for (int m = 0; m < 4; ++m) {
            float s = sw[b * 256 + m * 64 + c];
            Sw[(b * 4 + m) * 64 + c] = s;
            qb += s * db[m * 64 + c];
        }
        Qb[t] = qb;
    }
}

// ---------------------------------------------------------------------------
// Fold Sw into conv weights, bf16, pre-swizzled to MFMA B-fragment order:
// WB[b][chunk(4)][tpair(18)][co(64)][k32], k = tpl*16 + cil.
// ---------------------------------------------------------------------------
__global__ __launch_bounds__(256) void k_fold(const float* __restrict__ dw,
                                              const float* __restrict__ Sw,
                                              short* __restrict__ WB) {
    int idx = blockIdx.x * 256 + threadIdx.x;   // 589824 total
    int kk = idx & 31;
    int co = (idx >> 5) & 63;
    int rest = idx >> 11;            // [0,288)
    int tpair = rest % 18;
    int bc = rest / 18;              // [0,16)
    int chunk = bc & 3, b = bc >> 2;
    int tpl = kk >> 4, cil = kk & 15;
    int tap = 2 * tpair + tpl;
    int m = tap / 9, k9 = tap % 9;
    int ci = chunk * 16 + cil;
    float val = Sw[(b * 4 + m) * 64 + co] * dw[(size_t)((m * 64 + co) * 64 + ci) * 9 + k9];
    WB[idx] = f2bf(val);
}

// ---------------------------------------------------------------------------
// MFMA implicit-GEMM fused 4-dilation conv -> Q (bf16 NHWC).
// ---------------------------------------------------------------------------
__global__ __launch_bounds__(128) void k_convm(const float* __restrict__ xln,
                                               const short* __restrict__ WB,
                                               const float* __restrict__ Qb,
                                               short* __restrict__ Qs) {
    const int wt = blockIdx.x, h = blockIdx.y, b = blockIdx.z;
    const int t = threadIdx.x;
    const int lane = t & 63, wave = t >> 6;
    const int g = lane >> 4, ln15 = lane & 15;
    __shared__ short tile[2 * 9 * 144 * 8];   // [half][r][col][ci8]

    f32x4 acc[4][4];
    {
        float qb[4];
#pragma unroll
        for (int nt = 0; nt < 4; ++nt) qb[nt] = Qb[b * 64 + nt * 16 + ln15];
#pragma unroll
        for (int mt = 0; mt < 4; ++mt)
#pragma unroll
            for (int nt = 0; nt < 4; ++nt)
                acc[mt][nt] = (f32x4){qb[nt], qb[nt], qb[nt], qb[nt]};
    }
    const int w0 = wt * 128;
    const int laneelem = (wave * 64 + ln15) * 8;
    const int halfoff = (g & 1) * (9 * 144 * 8);
    const int tsel = g >> 1;

    for (int chunk = 0; chunk < 4; ++chunk) {
        __syncthreads();
        for (int slot = t; slot < 9 * 144 * 4; slot += 128) {
            int col = slot % 144;
            int rc = slot / 144;
            int r = rc % 9;
            int cg = rc / 9;
            int gh = h + 2 * r - 8;
            int gw = w0 - 8 + col;
            float f0 = 0.f, f1 = 0.f, f2 = 0.f, f3 = 0.f;
            if (gh >= 0 && gh < NH && gw >= 0 && gw < NW) {
                const float* p = xln + ((size_t)(b * 64 + chunk * 16 + cg * 4) * NH + gh) * NW + gw;
                f0 = p[0]; f1 = p[HWp]; f2 = p[2 * HWp]; f3 = p[3 * HWp];
            }
            short4t sv = {f2bf(f0), f2bf(f1), f2bf(f2), f2bf(f3)};
            short* dst = tile + (cg >= 2 ? 9 * 144 * 8 : 0) + (r * 144 + col) * 8 + (cg & 1) * 4;
            *(short4t*)dst = sv;
        }
        __syncthreads();

        const short* wbase = WB + (size_t)((b * 4 + chunk) * 18) * 2048 + ln15 * 32 + g * 8;
        for (int tp = 0; tp < 18; ++tp) {
            int ta = 2 * tp, tb = ta + 1;
            int ma = ta / 9, k9a = ta % 9;
            int mb = tb / 9, k9b = tb % 9;
            int offA = ((4 + (ma + 1) * (k9a / 3 - 1)) * 144 + 8 + 2 * (ma + 1) * (k9a % 3 - 1)) * 8;
            int offB = ((4 + (mb + 1) * (k9b / 3 - 1)) * 144 + 8 + 2 * (mb + 1) * (k9b % 3 - 1)) * 8;
            int aoff = (tsel ? offB : offA) + laneelem + halfoff;
            const short* ap = tile + aoff;
            short8 a0 = *(const short8*)(ap);
            short8 a1 = *(const short8*)(ap + 128);
            short8 a2 = *(const short8*)(ap + 256);
            short8 a3 = *(const short8*)(ap + 384);
            const short* bp = wbase + (size_t)tp * 2048;
            short8 b0 = *(const short8*)(bp);
            short8 b1 = *(const short8*)(bp + 512);
            short8 b2 = *(const short8*)(bp + 1024);
            short8 b3 = *(const short8*)(bp + 1536);
            acc[0][0] = __builtin_amdgcn_mfma_f32_16x16x32_bf16(a0, b0, acc[0][0], 0, 0, 0);
            acc[0][1] = __builtin_amdgcn_mfma_f32_16x16x32_bf16(a0, b1, acc[0][1], 0, 0, 0);
            acc[0][2] = __builtin_amdgcn_mfma_f32_16x16x32_bf16(a0, b2, acc[0][2], 0, 0, 0);
            acc[0][3] = __builtin_amdgcn_mfma_f32_16x16x32_bf16(a0, b3, acc[0][3], 0, 0, 0);
            acc[1][0] = __builtin_amdgcn_mfma_f32_16x16x32_bf16(a1, b0, acc[1][0], 0, 0, 0);
            acc[1][1] = __builtin_amdgcn_mfma_f32_16x16x32_bf16(a1, b1, acc[1][1], 0, 0, 0);
            acc[1][2] = __builtin_amdgcn_mfma_f32_16x16x32_bf16(a1, b2, acc[1][2], 0, 0, 0);
            acc[1][3] = __builtin_amdgcn_mfma_f32_16x16x32_bf16(a1, b3, acc[1][3], 0, 0, 0);
            acc[2][0] = __builtin_amdgcn_mfma_f32_16x16x32_bf16(a2, b0, acc[2][0], 0, 0, 0);
            acc[2][1] = __builtin_amdgcn_mfma_f32_16x16x32_bf16(a2, b1, acc[2][1], 0, 0, 0);
            acc[2][2] = __builtin_amdgcn_mfma_f32_16x16x32_bf16(a2, b2, acc[2][2], 0, 0, 0);
            acc[2][3] = __builtin_amdgcn_mfma_f32_16x16x32_bf16(a2, b3, acc[2][3], 0, 0, 0);
            acc[3][0] = __builtin_amdgcn_mfma_f32_16x16x32_bf16(a3, b0, acc[3][0], 0, 0, 0);
            acc[3][1] = __builtin_amdgcn_mfma_f32_16x16x32_bf16(a3, b1, acc[3][1], 0, 0, 0);
            acc[3][2] = __builtin_amdgcn_mfma_f32_16x16x32_bf16(a3, b2, acc[3][2], 0, 0, 0);
            acc[3][3] = __builtin_amdgcn_mfma_f32_16x16x32_bf16(a3, b3, acc[3][3], 0, 0, 0);
        }
    }
    // epilogue: D row=(lane>>4)*4+j (px), col=lane&15 (co); store bf16 NHWC
#pragma unroll
    for (int mt = 0; mt < 4; ++mt) {
        int px = w0 + wave * 64 + mt * 16 + (lane >> 4) * 4;
#pragma unroll
        for (int j = 0; j < 4; ++j) {
            short* qp = Qs + ((size_t)(b * NH + h) * NW + px + j) * 64 + ln15;
            qp[0]  = f2bf(acc[mt][0][j]);
            qp[16] = f2bf(acc[mt][1][j]);
            qp[32] = f2bf(acc[mt][2][j]);
            qp[48] = f2bf(acc[mt][3][j]);
        }
    }
}

// ---------------------------------------------------------------------------
// 1x1 conv V = x @ w2^T + b2, output bf16 "NCHW w-permuted": per 64-w tile,
// VT[b][c][h][wt*64 + s] = V[wt*64 + u(s)][c],  u(s) = (s>>2) + 16*(s&3).
// This makes PV B-fragments in k_attn contiguous 16B global loads.
// ---------------------------------------------------------------------------
__global__ __launch_bounds__(256) void k_v(const float* __restrict__ x,
                                           const float* __restrict__ w2,
                                           const float* __restrict__ b2,
                                           short* __restrict__ VT) {
    int wt = blockIdx.x, h = blockIdx.y, b = blockIdx.z;
    int t = threadIdx.x, c = t & 63, q = t >> 6;
    __shared__ float xs[64 * 65];
    int w0 = wt * 64;
    const float* src = x + (size_t)(b * 64) * HWp + h * NW + w0;
    for (int idx = t; idx < 4096; idx += 256) {
        int ci = idx >> 6, col = idx & 63;
        xs[ci * 65 + col] = src[(size_t)ci * HWp + col];
    }
    float wreg[64];
    const float* wrow = w2 + c * 64;
#pragma unroll
    for (int k = 0; k < 16; ++k) {
        float4 f = ((const float4*)wrow)[k];
        wreg[4 * k] = f.x; wreg[4 * k + 1] = f.y; wreg[4 * k + 2] = f.z; wreg[4 * k + 3] = f.w;
    }
    __syncthreads();
    float acc[16];
    float bias = b2[c];
#pragma unroll
    for (int p = 0; p < 16; ++p) acc[p] = bias;
#pragma unroll
    for (int ci = 0; ci < 64; ++ci) {
        float wv = wreg[ci];
        const float* xrow = xs + ci * 65 + q * 16;
#pragma unroll
        for (int p2 = 0; p2 < 8; ++p2) {
            float2 in2 = *(const float2*)(xrow + 2 * p2);
            acc[2 * p2]     += wv * in2.x;
            acc[2 * p2 + 1] += wv * in2.y;
        }
    }
    // transpose through LDS: xs[c][w_local] = V[w_local][c]
    __syncthreads();
#pragma unroll
    for (int p = 0; p < 16; ++p) xs[c * 65 + q * 16 + p] = acc[p];
    __syncthreads();
    {
        int s = t & 63, g2 = t >> 6;
        int u = (s >> 2) + 16 * (s & 3);
        for (int cc = 0; cc < 16; ++cc) {
            int ch = g2 * 16 + cc;
            VT[((size_t)(b * 64 + ch) * NH + h) * NW + w0 + s] = f2bf(xs[ch * 65 + u]);
        }
    }
}

// ---------------------------------------------------------------------------
// Fused cross-attention, flash-style, both QK^T and PV on MFMA.
// Grid (2, NH, NB), 128 thr = 2 waves. Wave owns 64 query rows.
// out[b][c][h][w] = xres + scl[c] * softmax_row(Qa·Qb^T/8) @ V
// Qa,Qb: bf16 NHWC. VT: bf16 NCHW w-permuted (see k_v).
// P transposed C-layout -> A-layout via per-wave-private LDS (no barriers),
// with k-permutation s(u) = (u&15)*4 + (u>>4) so writes are b64, reads b128.
// ---------------------------------------------------------------------------
__global__ __launch_bounds__(128, 2) void k_attn(const short* __restrict__ Qa,
                                                 const short* __restrict__ Qbp,
                                                 const short* __restrict__ VT,
                                                 const float* __restrict__ xres,
                                                 const float* __restrict__ scl,
                                                 float* __restrict__ out) {
    const int bx = blockIdx.x, h = blockIdx.y, b = blockIdx.z;
    const int t = threadIdx.x, lane = t & 63, wave = t >> 6;
    const int q = lane >> 4, c15 = lane & 15;
    __shared__ __align__(16) short PB[2][64 * 72];
    short* pb = PB[wave];

    const int wbase = bx * 128 + wave * 64;
    const short* qabase = Qa + ((size_t)(b * NH + h) * NW + wbase) * 64;
    const short* qbbase = Qbp + ((size_t)(b * NH + h) * NW) * 64;

    // preload A-fragments (Qa rows) into registers
    short8 afrag[4][2];
#pragma unroll
    for (int mt = 0; mt < 4; ++mt)
#pragma unroll
        for (int kk = 0; kk < 2; ++kk)
            afrag[mt][kk] = *(const short8*)(qabase + (mt * 16 + c15) * 64 + kk * 32 + q * 8);

    f32x4 osum[4][4];
#pragma unroll
    for (int mt = 0; mt < 4; ++mt)
#pragma unroll
        for (int nt = 0; nt < 4; ++nt) osum[mt][nt] = (f32x4){0.f, 0.f, 0.f, 0.f};
    float mrow[16], lrow[16];
#pragma unroll
    for (int i = 0; i < 16; ++i) { mrow[i] = -1e30f; lrow[i] = 0.f; }

    for (int vt = 0; vt < 4; ++vt) {
        // ---- S tile = Qa · Qb^T ----
        f32x4 s[4][4];
#pragma unroll
        for (int mt = 0; mt < 4; ++mt)
#pragma unroll
            for (int nt = 0; nt < 4; ++nt) s[mt][nt] = (f32x4){0.f, 0.f, 0.f, 0.f};
#pragma unroll
        for (int kk = 0; kk < 2; ++kk) {
            short8 bq[4];
#pragma unroll
            for (int nt = 0; nt < 4; ++nt)
                bq[nt] = *(const short8*)(qbbase + (size_t)(vt * 64 + nt * 16 + c15) * 64 + kk * 32 + q * 8);
#pragma unroll
            for (int mt = 0; mt < 4; ++mt)
#pragma unroll
                for (int nt = 0; nt < 4; ++nt)
                    s[mt][nt] = __builtin_amdgcn_mfma_f32_16x16x32_bf16(afrag[mt][kk], bq[nt], s[mt][nt], 0, 0, 0);
        }
        // ---- scale + online softmax stats ----
#pragma unroll
        for (int mt = 0; mt < 4; ++mt)
#pragma unroll
            for (int nt = 0; nt < 4; ++nt)
#pragma unroll
                for (int r = 0; r < 4; ++r) s[mt][nt][r] *= 0.125f;
        float al[16];
#pragma unroll
        for (int mt = 0; mt < 4; ++mt)
#pragma unroll
            for (int r = 0; r < 4; ++r) {
                float m0 = fmaxf(fmaxf(s[mt][0][r], s[mt][1][r]), fmaxf(s[mt][2][r], s[mt][3][r]));
#pragma unroll
                for (int msk = 1; msk < 16; msk <<= 1) m0 = fmaxf(m0, __shfl_xor(m0, msk, 64));
                int i = mt * 4 + r;
                float mn = fmaxf(mrow[i], m0);
                al[i] = __expf(mrow[i] - mn);
                mrow[i] = mn;
            }
        // ---- P = exp(s - m): write to LDS (b64, k-permuted), row sums ----
#pragma unroll
        for (int mt = 0; mt < 4; ++mt)
#pragma unroll
            for (int r = 0; r < 4; ++r) {
                int i = mt * 4 + r;
                float m = mrow[i];
                float p0 = __expf(s[mt][0][r] - m);
                float p1 = __expf(s[mt][1][r] - m);
                float p2 = __expf(s[mt][2][r] - m);
                float p3 = __expf(s[mt][3][r] - m);
                short4t pk = {f2bf(p0), f2bf(p1), f2bf(p2), f2bf(p3)};
                *(short4t*)(pb + (mt * 16 + q * 4 + r) * 72 + c15 * 4) = pk;
                float lsv = (p0 + p1) + (p2 + p3);
#pragma unroll
                for (int msk = 1; msk < 16; msk <<= 1) lsv += __shfl_xor(lsv, msk, 64);
                lrow[i] = lrow[i] * al[i] + lsv;
            }
        // ---- rescale O ----
#pragma unroll
        for (int mt = 0; mt < 4; ++mt)
#pragma unroll
            for (int nt = 0; nt < 4; ++nt)
#pragma unroll
                for (int r = 0; r < 4; ++r) osum[mt][nt][r] *= al[mt * 4 + r];
        // ---- O += P · V  (k index = s, V pre-permuted in global) ----
#pragma unroll
        for (int kk = 0; kk < 2; ++kk) {
            short8 ap[4], bv[4];
#pragma unroll
            for (int mt = 0; mt < 4; ++mt)
                ap[mt] = *(const short8*)(pb + (mt * 16 + c15) * 72 + kk * 32 + q * 8);
#pragma unroll
            for (int nt = 0; nt < 4; ++nt)
                bv[nt] = *(const short8*)(VT + ((size_t)(b * 64 + nt * 16 + c15) * NH + h) * NW + vt * 64 + kk * 32 + q * 8);
#pragma unroll
            for (int mt = 0; mt < 4; ++mt)
#pragma unroll
                for (int nt = 0; nt < 4; ++nt)
                    osum[mt][nt] = __builtin_amdgcn_mfma_f32_16x16x32_bf16(ap[mt], bv[nt], osum[mt][nt], 0, 0, 0);
        }
    }
    // ---- epilogue: out = xres + O/l * scl ----
    float linv[16];
#pragma unroll
    for (int i = 0; i < 16; ++i) linv[i] = 1.f / lrow[i];
#pragma unroll
    for (int nt = 0; nt < 4; ++nt) {
        int c = nt * 16 + c15;
        float bv = scl[c];
        size_t pbase = ((size_t)(b * 64 + c) * NH + h) * NW + wbase;
#pragma unroll
        for (int mt = 0; mt < 4; ++mt)
#pragma unroll
            for (int r = 0; r < 4; ++r) {
                size_t o = pbase + mt * 16 + q * 4 + r;
                out[o] = xres[o] + osum[mt][nt][r] * linv[mt * 4 + r] * bv;
            }
    }
}

// ---------------------------------------------------------------------------
extern "C" void kernel_launch(void* const* d_in, const int* in_sizes, int n_in,
                              void* d_out, int out_size, void* d_ws, size_t ws_size,
                              hipStream_t stream) {
    const float* x_l   = (const float*)d_in[0];
    const float* x_r   = (const float*)d_in[1];
    const float* lnl_g = (const float*)d_in[2];
    const float* lnl_b = (const float*)d_in[3];
    const float* lnr_g = (const float*)d_in[4];
    const float* lnr_b = (const float*)d_in[5];
    const float* l_dw  = (const float*)d_in[6];
    const float* l_db  = (const float*)d_in[7];
    const float* l_c1w = (const float*)d_in[8];
    const float* l_c1b = (const float*)d_in[9];
    const float* l_pw  = (const float*)d_in[10];
    const float* r_dw  = (const float*)d_in[11];
    const float* r_db  = (const float*)d_in[12];
    const float* r_c1w = (const float*)d_in[13];
    const float* r_c1b = (const float*)d_in[14];
    const float* r_pw  = (const float*)d_in[15];
    const float* l2w   = (const float*)d_in[16];
    const float* l2b   = (const float*)d_in[17];
    const float* r2w   = (const float*)d_in[18];
    const float* r2b   = (const float*)d_in[19];
    const float* beta  = (const float*)d_in[20];
    const float* gamma = (const float*)d_in[21];
    float* out = (float*)d_out;

    constexpr size_t PLANE = (size_t)NB * NC * NH * NW;   // 6291456
    float* ws = (float*)d_ws;
    float* XLN = ws;                 ws += PLANE;
    short* QLs = (short*)ws;         ws += PLANE / 2;
    short* QRs = (short*)ws;         ws += PLANE / 2;
    short* VLs = (short*)ws;         ws += PLANE / 2;
    short* VRs = (short*)ws;         ws += PLANE / 2;
    short* WB  = (short*)ws;         ws += 294912;   // 589824 bf16
    float* Tb  = ws;                 ws += 9216;
    float* SW  = ws;                 ws += 1024;
    float* QB  = ws;                 ws += 256;

    dim3 blk(256);
    // --- left SKM ---
    k_ln    <<<dim3(NH, NB), blk, 0, stream>>>(x_l, lnl_g, lnl_b, XLN);
    k_rect  <<<dim3(NB * NC), blk, 0, stream>>>(XLN, Tb);
    k_select<<<dim3(1), blk, 0, stream>>>(Tb, l_dw, l_db, l_c1w, l_c1b, l_pw, SW, QB);
    k_fold  <<<dim3(2304), blk, 0, stream>>>(l_dw, SW, WB);
    k_convm <<<dim3(2, NH, NB), dim3(128), 0, stream>>>(XLN, WB, QB, QLs);
    k_v     <<<dim3(4, NH, NB), blk, 0, stream>>>(x_l, l2w, l2b, VLs);
    // --- right SKM ---
    k_ln    <<<dim3(NH, NB), blk, 0, stream>>>(x_r, lnr_g, lnr_b, XLN);
    k_rect  <<<dim3(NB * NC), blk, 0, stream>>>(XLN, Tb);
    k_select<<<dim3(1), blk, 0, stream>>>(Tb, r_dw, r_db, r_c1w, r_c1b, r_pw, SW, QB);
    k_fold  <<<dim3(2304), blk, 0, stream>>>(r_dw, SW, WB);
    k_convm <<<dim3(2, NH, NB), dim3(128), 0, stream>>>(XLN, WB, QB, QRs);
    k_v     <<<dim3(4, NH, NB), blk, 0, stream>>>(x_r, r2w, r2b, VRs);
    // --- fused cross attention (both directions) ---
    k_attn  <<<dim3(2, NH, NB), dim3(128), 0, stream>>>(QLs, QRs, VRs, x_l, beta, out);
    k_attn  <<<dim3(2, NH, NB), dim3(128), 0, stream>>>(QRs, QLs, VLs, x_r, gamma, out + PLANE);
}

// Round 4
// 729.062 us; speedup vs baseline: 1.4485x; 1.4485x over previous
//
#include <hip/hip_runtime.h>
#include <hip/hip_bf16.h>
#include <cstdint>

// Problem constants (B,C,H,W fixed by setup_inputs)
constexpr int NB = 4;
constexpr int NC = 64;
constexpr int NH = 96;
constexpr int NW = 256;
constexpr int HWp = NH * NW;          // 24576 pixels per plane
constexpr float EPS = 1e-6f;

typedef __attribute__((ext_vector_type(8))) short short8;
typedef __attribute__((ext_vector_type(4))) short short4t;
typedef __attribute__((ext_vector_type(4))) float f32x4;

static __device__ __forceinline__ short f2bf(float f) {
    __hip_bfloat16 h = __float2bfloat16(f);
    return *reinterpret_cast<short*>(&h);
}

// ---------------------------------------------------------------------------
// LayerNorm2d over channels at each (b,h,w). Block = one (b,h) row, 256 thr.
// ---------------------------------------------------------------------------
__global__ __launch_bounds__(256) void k_ln(const float* __restrict__ x,
                                            const float* __restrict__ g,
                                            const float* __restrict__ bta,
                                            float* __restrict__ out) {
    int h = blockIdx.x, b = blockIdx.y, w = threadIdx.x;
    const float* xp = x + ((size_t)b * NC * NH + h) * NW + w;
    float v[64];
    float s = 0.f, sq = 0.f;
#pragma unroll
    for (int c = 0; c < 64; ++c) {
        float t = xp[(size_t)c * HWp];
        v[c] = t; s += t; sq += t * t;
    }
    float mu = s * (1.f / 64.f);
    float var = sq * (1.f / 64.f) - mu * mu;
    float rs = rsqrtf(var + EPS);
    float* op = out + ((size_t)b * NC * NH + h) * NW + w;
#pragma unroll
    for (int c = 0; c < 64; ++c) op[(size_t)c * HWp] = (v[c] - mu) * rs * g[c] + bta[c];
}

// ---------------------------------------------------------------------------
// Rectangle sums for the SKM global pool (D never materialized).
// T layout: [b][m][ci][9]
// ---------------------------------------------------------------------------
__global__ __launch_bounds__(256) void k_rect(const float* __restrict__ xln,
                                              float* __restrict__ T) {
    int bci = blockIdx.x;
    int b = bci >> 6, ci = bci & 63;
    int t = threadIdx.x, lane = t & 63, wv = t >> 6;
    __shared__ float rp[NH][9];
    const float* base = xln + (size_t)bci * HWp;
    for (int r = wv; r < NH; r += 4) {
        float4 vv = *(const float4*)(base + r * NW + lane * 4);
        float a = vv.x + vv.y, bb = vv.z + vv.w;
        float s4 = a + bb;
        float full = s4;
#pragma unroll
        for (int o = 32; o; o >>= 1) full += __shfl_xor(full, o, 64);
        float l0a = __shfl(a, 0, 64),  l0s = __shfl(s4, 0, 64);
        float l1a = __shfl(a, 1, 64),  l1s = __shfl(s4, 1, 64);
        float r63b = __shfl(bb, 63, 64), r63s = __shfl(s4, 63, 64);
        float r62b = __shfl(bb, 62, 64), r62s = __shfl(s4, 62, 64);
        if (lane == 0) {
            rp[r][0] = full;
            rp[r][1] = l0a;  rp[r][2] = l0s;  rp[r][3] = l0s + l1a;  rp[r][4] = l0s + l1s;
            rp[r][5] = r63b; rp[r][6] = r63s; rp[r][7] = r63s + r62b; rp[r][8] = r63s + r62s;
        }
    }
    __syncthreads();
    if (t < 36) {
        int m = t / 9, kh = (t % 9) / 3, kw = t % 3;
        int d = 2 * (m + 1);
        int r0 = (kh == 2) ? d : 0;
        int r1 = (kh == 0) ? NH - d : NH;
        float s = 0.f;
        for (int r = r0; r < r1; ++r) {
            float rowv = rp[r][0];
            if (kw == 0) rowv -= rp[r][5 + m];
            else if (kw == 2) rowv -= rp[r][1 + m];
            s += rowv;
        }
        T[(((b * 4 + m) * 64) + ci) * 9 + kh * 3 + kw] = s;
    }
}

// ---------------------------------------------------------------------------
// SKM selection MLP: Z -> S -> P -> softmax over C -> Sw, plus folded bias.
// ---------------------------------------------------------------------------
__global__ __launch_bounds__(256) void k_select(const float* __restrict__ T,
                                                const float* __restrict__ dw,
                                                const float* __restrict__ db,
                                                const float* __restrict__ c1w,
                                                const float* __restrict__ c1b,
                                                const float* __restrict__ pw,
                                                float* __restrict__ Sw,
                                                float* __restrict__ Qb) {
    int t = threadIdx.x;
    __shared__ float zs[256], ss[512], ps[1024], sw[1024];
    {
        int b = t >> 6, c = t & 63;
        float acc = 0.f, bias = 0.f;
        for (int m = 0; m < 4; ++m) {
            const float* wp = dw + (size_t)(m * 64 + c) * 576;
            const float* tp = T + (size_t)(b * 4 + m) * 576;
            float a2 = 0.f;
            for (int j = 0; j < 576; ++j) a2 += wp[j] * tp[j];
            acc += a2;
            bias += db[m * 64 + c];
        }
        zs[t] = acc * (1.f / (float)HWp) + bias;
    }
    __syncthreads();
    for (int i = t; i < 512; i += 256) {
        int b = i >> 7, j = i & 127;
        float s = c1b[j];
        const float* wrow = c1w + j * 64;
        const float* zb = zs + b * 64;
        for (int c = 0; c < 64; ++c) s += zb[c] * wrow[c];
        ss[i] = fmaxf(s, 0.f);
    }
    __syncthreads();
    for (int i = t; i < 1024; i += 256) {
        int b = i >> 8, rem = i & 255;
        float p = 0.f;
        const float* sb = ss + b * 128;
        for (int j = 0; j < 128; ++j) p += sb[j] * pw[j * 256 + rem];
        ps[i] = p;
    }
    __syncthreads();
    if (t < 16) {
        int b = t >> 2, m = t & 3;
        const float* pp = ps + b * 256 + m * 64;
        float mx = -1e30f;
        for (int c = 0; c < 64; ++c) mx = fmaxf(mx, pp[c]);
        float sum = 0.f;
        for (int c = 0; c < 64; ++c) sum += expf(pp[c] - mx);
        float inv = 1.f / sum;
        for (int c = 0; c < 64; ++c) sw[b * 256 + m * 64 + c] = expf(pp[c] - mx) * inv;
    }
    __syncthreads();
    {
        int b = t >> 6, c = t & 63;
        float qb = 0.f;
#pragma unroll
        for (int m = 0; m < 4; ++m) {
            float s = sw[b * 256 + m * 64 + c];
            Sw[(b * 4 + m) * 64 + c] = s;
            qb += s * db[m * 64 + c];
        }
        Qb[t] = qb;
    }
}

// ---------------------------------------------------------------------------
// Fold Sw into conv weights, bf16, pre-swizzled to MFMA B-fragment order:
// WB[b][chunk(4)][tpair(18)][co(64)][k32], k = tpl*16 + cil.
// ---------------------------------------------------------------------------
__global__ __launch_bounds__(256) void k_fold(const float* __restrict__ dw,
                                              const float* __restrict__ Sw,
                                              short* __restrict__ WB) {
    int idx = blockIdx.x * 256 + threadIdx.x;   // 589824 total
    int kk = idx & 31;
    int co = (idx >> 5) & 63;
    int rest = idx >> 11;            // [0,288)
    int tpair = rest % 18;
    int bc = rest / 18;              // [0,16)
    int chunk = bc & 3, b = bc >> 2;
    int tpl = kk >> 4, cil = kk & 15;
    int tap = 2 * tpair + tpl;
    int m = tap / 9, k9 = tap % 9;
    int ci = chunk * 16 + cil;
    float val = Sw[(b * 4 + m) * 64 + co] * dw[(size_t)((m * 64 + co) * 64 + ci) * 9 + k9];
    WB[idx] = f2bf(val);
}

// ---------------------------------------------------------------------------
// MFMA implicit-GEMM fused 4-dilation conv -> Q (bf16 NHWC).
// ---------------------------------------------------------------------------
__global__ __launch_bounds__(128) void k_convm(const float* __restrict__ xln,
                                               const short* __restrict__ WB,
                                               const float* __restrict__ Qb,
                                               short* __restrict__ Qs) {
    const int wt = blockIdx.x, h = blockIdx.y, b = blockIdx.z;
    const int t = threadIdx.x;
    const int lane = t & 63, wave = t >> 6;
    const int g = lane >> 4, ln15 = lane & 15;
    __shared__ short tile[2 * 9 * 144 * 8];   // [half][r][col][ci8]

    f32x4 acc[4][4];
    {
        float qb[4];
#pragma unroll
        for (int nt = 0; nt < 4; ++nt) qb[nt] = Qb[b * 64 + nt * 16 + ln15];
#pragma unroll
        for (int mt = 0; mt < 4; ++mt)
#pragma unroll
            for (int nt = 0; nt < 4; ++nt)
                acc[mt][nt] = (f32x4){qb[nt], qb[nt], qb[nt], qb[nt]};
    }
    const int w0 = wt * 128;
    const int laneelem = (wave * 64 + ln15) * 8;
    const int halfoff = (g & 1) * (9 * 144 * 8);
    const int tsel = g >> 1;

    for (int chunk = 0; chunk < 4; ++chunk) {
        __syncthreads();
        for (int slot = t; slot < 9 * 144 * 4; slot += 128) {
            int col = slot % 144;
            int rc = slot / 144;
            int r = rc % 9;
            int cg = rc / 9;
            int gh = h + 2 * r - 8;
            int gw = w0 - 8 + col;
            float f0 = 0.f, f1 = 0.f, f2 = 0.f, f3 = 0.f;
            if (gh >= 0 && gh < NH && gw >= 0 && gw < NW) {
                const float* p = xln + ((size_t)(b * 64 + chunk * 16 + cg * 4) * NH + gh) * NW + gw;
                f0 = p[0]; f1 = p[HWp]; f2 = p[2 * HWp]; f3 = p[3 * HWp];
            }
            short4t sv = {f2bf(f0), f2bf(f1), f2bf(f2), f2bf(f3)};
            short* dst = tile + (cg >= 2 ? 9 * 144 * 8 : 0) + (r * 144 + col) * 8 + (cg & 1) * 4;
            *(short4t*)dst = sv;
        }
        __syncthreads();

        const short* wbase = WB + (size_t)((b * 4 + chunk) * 18) * 2048 + ln15 * 32 + g * 8;
        for (int tp = 0; tp < 18; ++tp) {
            int ta = 2 * tp, tb = ta + 1;
            int ma = ta / 9, k9a = ta % 9;
            int mb = tb / 9, k9b = tb % 9;
            int offA = ((4 + (ma + 1) * (k9a / 3 - 1)) * 144 + 8 + 2 * (ma + 1) * (k9a % 3 - 1)) * 8;
            int offB = ((4 + (mb + 1) * (k9b / 3 - 1)) * 144 + 8 + 2 * (mb + 1) * (k9b % 3 - 1)) * 8;
            int aoff = (tsel ? offB : offA) + laneelem + halfoff;
            const short* ap = tile + aoff;
            short8 a0 = *(const short8*)(ap);
            short8 a1 = *(const short8*)(ap + 128);
            short8 a2 = *(const short8*)(ap + 256);
            short8 a3 = *(const short8*)(ap + 384);
            const short* bp = wbase + (size_t)tp * 2048;
            short8 b0 = *(const short8*)(bp);
            short8 b1 = *(const short8*)(bp + 512);
            short8 b2 = *(const short8*)(bp + 1024);
            short8 b3 = *(const short8*)(bp + 1536);
            acc[0][0] = __builtin_amdgcn_mfma_f32_16x16x32_bf16(a0, b0, acc[0][0], 0, 0, 0);
            acc[0][1] = __builtin_amdgcn_mfma_f32_16x16x32_bf16(a0, b1, acc[0][1], 0, 0, 0);
            acc[0][2] = __builtin_amdgcn_mfma_f32_16x16x32_bf16(a0, b2, acc[0][2], 0, 0, 0);
            acc[0][3] = __builtin_amdgcn_mfma_f32_16x16x32_bf16(a0, b3, acc[0][3], 0, 0, 0);
            acc[1][0] = __builtin_amdgcn_mfma_f32_16x16x32_bf16(a1, b0, acc[1][0], 0, 0, 0);
            acc[1][1] = __builtin_amdgcn_mfma_f32_16x16x32_bf16(a1, b1, acc[1][1], 0, 0, 0);
            acc[1][2] = __builtin_amdgcn_mfma_f32_16x16x32_bf16(a1, b2, acc[1][2], 0, 0, 0);
            acc[1][3] = __builtin_amdgcn_mfma_f32_16x16x32_bf16(a1, b3, acc[1][3], 0, 0, 0);
            acc[2][0] = __builtin_amdgcn_mfma_f32_16x16x32_bf16(a2, b0, acc[2][0], 0, 0, 0);
            acc[2][1] = __builtin_amdgcn_mfma_f32_16x16x32_bf16(a2, b1, acc[2][1], 0, 0, 0);
            acc[2][2] = __builtin_amdgcn_mfma_f32_16x16x32_bf16(a2, b2, acc[2][2], 0, 0, 0);
            acc[2][3] = __builtin_amdgcn_mfma_f32_16x16x32_bf16(a2, b3, acc[2][3], 0, 0, 0);
            acc[3][0] = __builtin_amdgcn_mfma_f32_16x16x32_bf16(a3, b0, acc[3][0], 0, 0, 0);
            acc[3][1] = __builtin_amdgcn_mfma_f32_16x16x32_bf16(a3, b1, acc[3][1], 0, 0, 0);
            acc[3][2] = __builtin_amdgcn_mfma_f32_16x16x32_bf16(a3, b2, acc[3][2], 0, 0, 0);
            acc[3][3] = __builtin_amdgcn_mfma_f32_16x16x32_bf16(a3, b3, acc[3][3], 0, 0, 0);
        }
    }
    // epilogue: D row=(lane>>4)*4+j (px), col=lane&15 (co); store bf16 NHWC
#pragma unroll
    for (int mt = 0; mt < 4; ++mt) {
        int px = w0 + wave * 64 + mt * 16 + (lane >> 4) * 4;
#pragma unroll
        for (int j = 0; j < 4; ++j) {
            short* qp = Qs + ((size_t)(b * NH + h) * NW + px + j) * 64 + ln15;
            qp[0]  = f2bf(acc[mt][0][j]);
            qp[16] = f2bf(acc[mt][1][j]);
            qp[32] = f2bf(acc[mt][2][j]);
            qp[48] = f2bf(acc[mt][3][j]);
        }
    }
}

// ---------------------------------------------------------------------------
// 1x1 conv V = x @ w2^T + b2, output bf16 "NCHW w-permuted": per 64-w tile,
// VT[b][c][h][wt*64 + s] = V[wt*64 + u(s)][c],  u(s) = (s>>2) + 16*(s&3).
// Rewritten (R3 spilled wreg[64] -> VGPR demotion, 187 us): no per-thread
// arrays beyond acc[16]; both operands via ds_read_b128, <=2-way banked.
// Thread map: lane&15 -> px-group of 4, (lane>>4) -> c-sub of 4, wave -> c-quarter.
// ---------------------------------------------------------------------------
__global__ __launch_bounds__(256) void k_v(const float* __restrict__ x,
                                           const float* __restrict__ w2,
                                           const float* __restrict__ b2,
                                           short* __restrict__ VT) {
    int wt = blockIdx.x, h = blockIdx.y, b = blockIdx.z;
    int t = threadIdx.x, lane = t & 63, q = t >> 6;
    __shared__ float xs[64 * 68];    // [ci][px] then reused as [c][px]
    __shared__ float w2t[64 * 68];   // [ci][c]
    int w0 = wt * 64;
    const float* src = x + (size_t)(b * 64) * HWp + h * NW + w0;
    for (int idx = t; idx < 4096; idx += 256) {
        int ci = idx >> 6, col = idx & 63;
        xs[ci * 68 + col] = src[(size_t)ci * HWp + col];
    }
    for (int idx = t; idx < 4096; idx += 256) {
        int co = idx >> 6, ci = idx & 63;
        w2t[ci * 68 + co] = w2[co * 64 + ci];   // coalesced read, 8-way LDS write (64 instrs, ok)
    }
    __syncthreads();

    const int pl0 = (lane & 15) * 4;            // 4 px per thread
    const int c0 = q * 16 + (lane >> 4) * 4;    // 4 c per thread
    f32x4 a4[4];
#pragma unroll
    for (int cc = 0; cc < 4; ++cc) {
        float bb = b2[c0 + cc];
        a4[cc] = (f32x4){bb, bb, bb, bb};
    }
    for (int ci = 0; ci < 64; ++ci) {
        f32x4 xv = *(const f32x4*)(xs + ci * 68 + pl0);
        f32x4 wv = *(const f32x4*)(w2t + ci * 68 + c0);
        a4[0] += xv * wv[0];
        a4[1] += xv * wv[1];
        a4[2] += xv * wv[2];
        a4[3] += xv * wv[3];
    }
    // transpose through LDS: xs[c][px] = V[px][c]
    __syncthreads();
#pragma unroll
    for (int cc = 0; cc < 4; ++cc)
        *(f32x4*)(xs + (c0 + cc) * 68 + pl0) = a4[cc];
    __syncthreads();
    {
        int s = t & 63, g2 = t >> 6;
        int u = (s >> 2) + 16 * (s & 3);
#pragma unroll
        for (int cc = 0; cc < 16; ++cc) {
            int ch = g2 * 16 + cc;
            VT[((size_t)(b * 64 + ch) * NH + h) * NW + w0 + s] = f2bf(xs[ch * 68 + u]);
        }
    }
}

// ---------------------------------------------------------------------------
// Fused cross-attention, flash-style, both QK^T and PV on MFMA.
// Grid (2, NH, NB), 128 thr = 2 waves. Wave owns 64 query rows.
// out[b][c][h][w] = xres + scl[c] * softmax_row(Qa·Qb^T/8) @ V
// Qa,Qb: bf16 NHWC. VT: bf16 NCHW w-permuted (see k_v).
// P transposed C-layout -> A-layout via per-wave-private LDS (no barriers),
// with k-permutation s(u) = (u&15)*4 + (u>>4) so writes are b64, reads b128.
// ---------------------------------------------------------------------------
__global__ __launch_bounds__(128, 2) void k_attn(const short* __restrict__ Qa,
                                                 const short* __restrict__ Qbp,
                                                 const short* __restrict__ VT,
                                                 const float* __restrict__ xres,
                                                 const float* __restrict__ scl,
                                                 float* __restrict__ out) {
    const int bx = blockIdx.x, h = blockIdx.y, b = blockIdx.z;
    const int t = threadIdx.x, lane = t & 63, wave = t >> 6;
    const int q = lane >> 4, c15 = lane & 15;
    __shared__ __align__(16) short PB[2][64 * 72];
    short* pb = PB[wave];

    const int wbase = bx * 128 + wave * 64;
    const short* qabase = Qa + ((size_t)(b * NH + h) * NW + wbase) * 64;
    const short* qbbase = Qbp + ((size_t)(b * NH + h) * NW) * 64;

    // preload A-fragments (Qa rows) into registers
    short8 afrag[4][2];
#pragma unroll
    for (int mt = 0; mt < 4; ++mt)
#pragma unroll
        for (int kk = 0; kk < 2; ++kk)
            afrag[mt][kk] = *(const short8*)(qabase + (mt * 16 + c15) * 64 + kk * 32 + q * 8);

    f32x4 osum[4][4];
#pragma unroll
    for (int mt = 0; mt < 4; ++mt)
#pragma unroll
        for (int nt = 0; nt < 4; ++nt) osum[mt][nt] = (f32x4){0.f, 0.f, 0.f, 0.f};
    float mrow[16], lrow[16];
#pragma unroll
    for (int i = 0; i < 16; ++i) { mrow[i] = -1e30f; lrow[i] = 0.f; }

    for (int vt = 0; vt < 4; ++vt) {
        // ---- S tile = Qa · Qb^T ----
        f32x4 s[4][4];
#pragma unroll
        for (int mt = 0; mt < 4; ++mt)
#pragma unroll
            for (int nt = 0; nt < 4; ++nt) s[mt][nt] = (f32x4){0.f, 0.f, 0.f, 0.f};
#pragma unroll
        for (int kk = 0; kk < 2; ++kk) {
            short8 bq[4];
#pragma unroll
            for (int nt = 0; nt < 4; ++nt)
                bq[nt] = *(const short8*)(qbbase + (size_t)(vt * 64 + nt * 16 + c15) * 64 + kk * 32 + q * 8);
#pragma unroll
            for (int mt = 0; mt < 4; ++mt)
#pragma unroll
                for (int nt = 0; nt < 4; ++nt)
                    s[mt][nt] = __builtin_amdgcn_mfma_f32_16x16x32_bf16(afrag[mt][kk], bq[nt], s[mt][nt], 0, 0, 0);
        }
        // ---- scale + online softmax stats ----
#pragma unroll
        for (int mt = 0; mt < 4; ++mt)
#pragma unroll
            for (int nt = 0; nt < 4; ++nt)
#pragma unroll
                for (int r = 0; r < 4; ++r) s[mt][nt][r] *= 0.125f;
        float al[16];
#pragma unroll
        for (int mt = 0; mt < 4; ++mt)
#pragma unroll
            for (int r = 0; r < 4; ++r) {
                float m0 = fmaxf(fmaxf(s[mt][0][r], s[mt][1][r]), fmaxf(s[mt][2][r], s[mt][3][r]));
#pragma unroll
                for (int msk = 1; msk < 16; msk <<= 1) m0 = fmaxf(m0, __shfl_xor(m0, msk, 64));
                int i = mt * 4 + r;
                float mn = fmaxf(mrow[i], m0);
                al[i] = __expf(mrow[i] - mn);
                mrow[i] = mn;
            }
        // ---- P = exp(s - m): write to LDS (b64, k-permuted), row sums ----
#pragma unroll
        for (int mt = 0; mt < 4; ++mt)
#pragma unroll
            for (int r = 0; r < 4; ++r) {
                int i = mt * 4 + r;
                float m = mrow[i];
                float p0 = __expf(s[mt][0][r] - m);
                float p1 = __expf(s[mt][1][r] - m);
                float p2 = __expf(s[mt][2][r] - m);
                float p3 = __expf(s[mt][3][r] - m);
                short4t pk = {f2bf(p0), f2bf(p1), f2bf(p2), f2bf(p3)};
                *(short4t*)(pb + (mt * 16 + q * 4 + r) * 72 + c15 * 4) = pk;
                float lsv = (p0 + p1) + (p2 + p3);
#pragma unroll
                for (int msk = 1; msk < 16; msk <<= 1) lsv += __shfl_xor(lsv, msk, 64);
                lrow[i] = lrow[i] * al[i] + lsv;
            }
        // ---- rescale O ----
#pragma unroll
        for (int mt = 0; mt < 4; ++mt)
#pragma unroll
            for (int nt = 0; nt < 4; ++nt)
#pragma unroll
                for (int r = 0; r < 4; ++r) osum[mt][nt][r] *= al[mt * 4 + r];
        // ---- O += P · V  (k index = s, V pre-permuted in global) ----
#pragma unroll
        for (int kk = 0; kk < 2; ++kk) {
            short8 ap[4], bv[4];
#pragma unroll
            for (int mt = 0; mt < 4; ++mt)
                ap[mt] = *(const short8*)(pb + (mt * 16 + c15) * 72 + kk * 32 + q * 8);
#pragma unroll
            for (int nt = 0; nt < 4; ++nt)
                bv[nt] = *(const short8*)(VT + ((size_t)(b * 64 + nt * 16 + c15) * NH + h) * NW + vt * 64 + kk * 32 + q * 8);
#pragma unroll
            for (int mt = 0; mt < 4; ++mt)
#pragma unroll
                for (int nt = 0; nt < 4; ++nt)
                    osum[mt][nt] = __builtin_amdgcn_mfma_f32_16x16x32_bf16(ap[mt], bv[nt], osum[mt][nt], 0, 0, 0);
        }
    }
    // ---- epilogue: out = xres + O/l * scl ----
    float linv[16];
#pragma unroll
    for (int i = 0; i < 16; ++i) linv[i] = 1.f / lrow[i];
#pragma unroll
    for (int nt = 0; nt < 4; ++nt) {
        int c = nt * 16 + c15;
        float bv = scl[c];
        size_t pbase = ((size_t)(b * 64 + c) * NH + h) * NW + wbase;
#pragma unroll
        for (int mt = 0; mt < 4; ++mt)
#pragma unroll
            for (int r = 0; r < 4; ++r) {
                size_t o = pbase + mt * 16 + q * 4 + r;
                out[o] = xres[o] + osum[mt][nt][r] * linv[mt * 4 + r] * bv;
            }
    }
}

// ---------------------------------------------------------------------------
extern "C" void kernel_launch(void* const* d_in, const int* in_sizes, int n_in,
                              void* d_out, int out_size, void* d_ws, size_t ws_size,
                              hipStream_t stream) {
    const float* x_l   = (const float*)d_in[0];
    const float* x_r   = (const float*)d_in[1];
    const float* lnl_g = (const float*)d_in[2];
    const float* lnl_b = (const float*)d_in[3];
    const float* lnr_g = (const float*)d_in[4];
    const float* lnr_b = (const float*)d_in[5];
    const float* l_dw  = (const float*)d_in[6];
    const float* l_db  = (const float*)d_in[7];
    const float* l_c1w = (const float*)d_in[8];
    const float* l_c1b = (const float*)d_in[9];
    const float* l_pw  = (const float*)d_in[10];
    const float* r_dw  = (const float*)d_in[11];
    const float* r_db  = (const float*)d_in[12];
    const float* r_c1w = (const float*)d_in[13];
    const float* r_c1b = (const float*)d_in[14];
    const float* r_pw  = (const float*)d_in[15];
    const float* l2w   = (const float*)d_in[16];
    const float* l2b   = (const float*)d_in[17];
    const float* r2w   = (const float*)d_in[18];
    const float* r2b   = (const float*)d_in[19];
    const float* beta  = (const float*)d_in[20];
    const float* gamma = (const float*)d_in[21];
    float* out = (float*)d_out;

    constexpr size_t PLANE = (size_t)NB * NC * NH * NW;   // 6291456
    float* ws = (float*)d_ws;
    float* XLN = ws;                 ws += PLANE;
    short* QLs = (short*)ws;         ws += PLANE / 2;
    short* QRs = (short*)ws;         ws += PLANE / 2;
    short* VLs = (short*)ws;         ws += PLANE / 2;
    short* VRs = (short*)ws;         ws += PLANE / 2;
    short* WB  = (short*)ws;         ws += 294912;   // 589824 bf16
    float* Tb  = ws;                 ws += 9216;
    float* SW  = ws;                 ws += 1024;
    float* QB  = ws;                 ws += 256;

    dim3 blk(256);
    // --- left SKM ---
    k_ln    <<<dim3(NH, NB), blk, 0, stream>>>(x_l, lnl_g, lnl_b, XLN);
    k_rect  <<<dim3(NB * NC), blk, 0, stream>>>(XLN, Tb);
    k_select<<<dim3(1), blk, 0, stream>>>(Tb, l_dw, l_db, l_c1w, l_c1b, l_pw, SW, QB);
    k_fold  <<<dim3(2304), blk, 0, stream>>>(l_dw, SW, WB);
    k_convm <<<dim3(2, NH, NB), dim3(128), 0, stream>>>(XLN, WB, QB, QLs);
    k_v     <<<dim3(4, NH, NB), blk, 0, stream>>>(x_l, l2w, l2b, VLs);
    // --- right SKM ---
    k_ln    <<<dim3(NH, NB), blk, 0, stream>>>(x_r, lnr_g, lnr_b, XLN);
    k_rect  <<<dim3(NB * NC), blk, 0, stream>>>(XLN, Tb);
    k_select<<<dim3(1), blk, 0, stream>>>(Tb, r_dw, r_db, r_c1w, r_c1b, r_pw, SW, QB);
    k_fold  <<<dim3(2304), blk, 0, stream>>>(r_dw, SW, WB);
    k_convm <<<dim3(2, NH, NB), dim3(128), 0, stream>>>(XLN, WB, QB, QRs);
    k_v     <<<dim3(4, NH, NB), blk, 0, stream>>>(x_r, r2w, r2b, VRs);
    // --- fused cross attention (both directions) ---
    k_attn  <<<dim3(2, NH, NB), dim3(128), 0, stream>>>(QLs, QRs, VRs, x_l, beta, out);
    k_attn  <<<dim3(2, NH, NB), dim3(128), 0, stream>>>(QRs, QLs, VLs, x_r, gamma, out + PLANE);
}

// Round 5
// 542.293 us; speedup vs baseline: 1.9473x; 1.3444x over previous
//
#include <hip/hip_runtime.h>
#include <hip/hip_bf16.h>
#include <cstdint>

// Problem constants (B,C,H,W fixed by setup_inputs)
constexpr int NB = 4;
constexpr int NC = 64;
constexpr int NH = 96;
constexpr int NW = 256;
constexpr int HWp = NH * NW;          // 24576 pixels per plane
constexpr float EPS = 1e-6f;

typedef __attribute__((ext_vector_type(8))) short short8;
typedef __attribute__((ext_vector_type(4))) short short4t;
typedef __attribute__((ext_vector_type(4))) float f32x4;

static __device__ __forceinline__ short f2bf(float f) {
    __hip_bfloat16 h = __float2bfloat16(f);
    return *reinterpret_cast<short*>(&h);
}

// ---------------------------------------------------------------------------
// LayerNorm2d over channels at each (b,h,w). Block = one (b,h) row, 256 thr.
// ---------------------------------------------------------------------------
__global__ __launch_bounds__(256) void k_ln(const float* __restrict__ x,
                                            const float* __restrict__ g,
                                            const float* __restrict__ bta,
                                            float* __restrict__ out) {
    int h = blockIdx.x, b = blockIdx.y, w = threadIdx.x;
    const float* xp = x + ((size_t)b * NC * NH + h) * NW + w;
    float v[64];
    float s = 0.f, sq = 0.f;
#pragma unroll
    for (int c = 0; c < 64; ++c) {
        float t = xp[(size_t)c * HWp];
        v[c] = t; s += t; sq += t * t;
    }
    float mu = s * (1.f / 64.f);
    float var = sq * (1.f / 64.f) - mu * mu;
    float rs = rsqrtf(var + EPS);
    float* op = out + ((size_t)b * NC * NH + h) * NW + w;
#pragma unroll
    for (int c = 0; c < 64; ++c) op[(size_t)c * HWp] = (v[c] - mu) * rs * g[c] + bta[c];
}

// ---------------------------------------------------------------------------
// Rectangle sums for the SKM global pool (D never materialized).
// T layout: [b][m][ci][9]
// ---------------------------------------------------------------------------
__global__ __launch_bounds__(256) void k_rect(const float* __restrict__ xln,
                                              float* __restrict__ T) {
    int bci = blockIdx.x;
    int b = bci >> 6, ci = bci & 63;
    int t = threadIdx.x, lane = t & 63, wv = t >> 6;
    __shared__ float rp[NH][9];
    const float* base = xln + (size_t)bci * HWp;
    for (int r = wv; r < NH; r += 4) {
        float4 vv = *(const float4*)(base + r * NW + lane * 4);
        float a = vv.x + vv.y, bb = vv.z + vv.w;
        float s4 = a + bb;
        float full = s4;
#pragma unroll
        for (int o = 32; o; o >>= 1) full += __shfl_xor(full, o, 64);
        float l0a = __shfl(a, 0, 64),  l0s = __shfl(s4, 0, 64);
        float l1a = __shfl(a, 1, 64),  l1s = __shfl(s4, 1, 64);
        float r63b = __shfl(bb, 63, 64), r63s = __shfl(s4, 63, 64);
        float r62b = __shfl(bb, 62, 64), r62s = __shfl(s4, 62, 64);
        if (lane == 0) {
            rp[r][0] = full;
            rp[r][1] = l0a;  rp[r][2] = l0s;  rp[r][3] = l0s + l1a;  rp[r][4] = l0s + l1s;
            rp[r][5] = r63b; rp[r][6] = r63s; rp[r][7] = r63s + r62b; rp[r][8] = r63s + r62s;
        }
    }
    __syncthreads();
    if (t < 36) {
        int m = t / 9, kh = (t % 9) / 3, kw = t % 3;
        int d = 2 * (m + 1);
        int r0 = (kh == 2) ? d : 0;
        int r1 = (kh == 0) ? NH - d : NH;
        float s = 0.f;
        for (int r = r0; r < r1; ++r) {
            float rowv = rp[r][0];
            if (kw == 0) rowv -= rp[r][5 + m];
            else if (kw == 2) rowv -= rp[r][1 + m];
            s += rowv;
        }
        T[(((b * 4 + m) * 64) + ci) * 9 + kh * 3 + kw] = s;
    }
}

// ---------------------------------------------------------------------------
// Z[b,c] = (1/HW) * sum_m dot(dw[m,c,:], T[b,m,:]) + sum_m db[m,c]
// Grid 256 blocks (b*64+c), 256 thr = 4 waves (wave = m). Coalesced dw reads.
// (R4: this was a single-block serial loop inside k_select -> 111 us.)
// ---------------------------------------------------------------------------
__global__ __launch_bounds__(256) void k_z(const float* __restrict__ T,
                                           const float* __restrict__ dw,
                                           const float* __restrict__ db,
                                           float* __restrict__ Z) {
    int bc = blockIdx.x;
    int b = bc >> 6, c = bc & 63;
    int t = threadIdx.x, lane = t & 63, m = t >> 6;
    const float* wp = dw + (size_t)(m * 64 + c) * 576;
    const float* tp = T + (size_t)(b * 4 + m) * 576;
    float s = 0.f;
    for (int j = lane; j < 576; j += 64) s += wp[j] * tp[j];
#pragma unroll
    for (int o = 32; o; o >>= 1) s += __shfl_xor(s, o, 64);
    __shared__ float red[4];
    if (lane == 0) red[m] = s;
    __syncthreads();
    if (t == 0) {
        float z = (red[0] + red[1]) + (red[2] + red[3]);
        float bias = db[c] + db[64 + c] + db[128 + c] + db[192 + c];
        Z[bc] = z * (1.f / (float)HWp) + bias;
    }
}

// ---------------------------------------------------------------------------
// Selection MLP tail: S=relu(Z@c1w^T+c1b); P=S@pw; softmax over c per m;
// Sw + folded bias Qb. Grid 4 (one block per batch), 256 thr.
// ---------------------------------------------------------------------------
__global__ __launch_bounds__(256) void k_sel2(const float* __restrict__ Z,
                                              const float* __restrict__ db,
                                              const float* __restrict__ c1w,
                                              const float* __restrict__ c1b,
                                              const float* __restrict__ pw,
                                              float* __restrict__ Sw,
                                              float* __restrict__ Qb) {
    int b = blockIdx.x;
    int t = threadIdx.x, lane = t & 63, wv = t >> 6;
    __shared__ float zs[64], ss[128], sw[256];
    __shared__ float cw[128 * 64];
    if (t < 64) zs[t] = Z[b * 64 + t];
    for (int i = t; i < 8192; i += 256) cw[i] = c1w[i];
    __syncthreads();
    if (t < 128) {
        float s = c1b[t];
        const float* wrow = cw + t * 64;
        for (int c = 0; c < 64; ++c) s += zs[c] * wrow[c];
        ss[t] = fmaxf(s, 0.f);
    }
    __syncthreads();
    // ps[rem=t] = dot(ss, pw[:,t]) — coalesced across lanes
    float p = 0.f;
    for (int j = 0; j < 128; ++j) p += ss[j] * pw[j * 256 + t];
    // softmax over c within each m: wave wv = m, lane = c
    float mx = p;
#pragma unroll
    for (int o = 32; o; o >>= 1) mx = fmaxf(mx, __shfl_xor(mx, o, 64));
    float e = __expf(p - mx);
    float sum = e;
#pragma unroll
    for (int o = 32; o; o >>= 1) sum += __shfl_xor(sum, o, 64);
    float swv = e / sum;
    Sw[(b * 4 + wv) * 64 + lane] = swv;
    sw[wv * 64 + lane] = swv;
    __syncthreads();
    if (t < 64) {
        float qb = sw[t] * db[t] + sw[64 + t] * db[64 + t]
                 + sw[128 + t] * db[128 + t] + sw[192 + t] * db[192 + t];
        Qb[b * 64 + t] = qb;
    }
}

// ---------------------------------------------------------------------------
// Fold Sw into conv weights, bf16, pre-swizzled to MFMA B-fragment order:
// WB[b][chunk(4)][tpair(18)][co(64)][k32], k = tpl*16 + cil.
// ---------------------------------------------------------------------------
__global__ __launch_bounds__(256) void k_fold(const float* __restrict__ dw,
                                              const float* __restrict__ Sw,
                                              short* __restrict__ WB) {
    int idx = blockIdx.x * 256 + threadIdx.x;   // 589824 total
    int kk = idx & 31;
    int co = (idx >> 5) & 63;
    int rest = idx >> 11;            // [0,288)
    int tpair = rest % 18;
    int bc = rest / 18;              // [0,16)
    int chunk = bc & 3, b = bc >> 2;
    int tpl = kk >> 4, cil = kk & 15;
    int tap = 2 * tpair + tpl;
    int m = tap / 9, k9 = tap % 9;
    int ci = chunk * 16 + cil;
    float val = Sw[(b * 4 + m) * 64 + co] * dw[(size_t)((m * 64 + co) * 64 + ci) * 9 + k9];
    WB[idx] = f2bf(val);
}

// ---------------------------------------------------------------------------
// MFMA implicit-GEMM fused 4-dilation conv -> Q (bf16 NHWC).
// ---------------------------------------------------------------------------
__global__ __launch_bounds__(128) void k_convm(const float* __restrict__ xln,
                                               const short* __restrict__ WB,
                                               const float* __restrict__ Qb,
                                               short* __restrict__ Qs) {
    const int wt = blockIdx.x, h = blockIdx.y, b = blockIdx.z;
    const int t = threadIdx.x;
    const int lane = t & 63, wave = t >> 6;
    const int g = lane >> 4, ln15 = lane & 15;
    __shared__ short tile[2 * 9 * 144 * 8];   // [half][r][col][ci8]

    f32x4 acc[4][4];
    {
        float qb[4];
#pragma unroll
        for (int nt = 0; nt < 4; ++nt) qb[nt] = Qb[b * 64 + nt * 16 + ln15];
#pragma unroll
        for (int mt = 0; mt < 4; ++mt)
#pragma unroll
            for (int nt = 0; nt < 4; ++nt)
                acc[mt][nt] = (f32x4){qb[nt], qb[nt], qb[nt], qb[nt]};
    }
    const int w0 = wt * 128;
    const int laneelem = (wave * 64 + ln15) * 8;
    const int halfoff = (g & 1) * (9 * 144 * 8);
    const int tsel = g >> 1;

    for (int chunk = 0; chunk < 4; ++chunk) {
        __syncthreads();
        for (int slot = t; slot < 9 * 144 * 4; slot += 128) {
            int col = slot % 144;
            int rc = slot / 144;
            int r = rc % 9;
            int cg = rc / 9;
            int gh = h + 2 * r - 8;
            int gw = w0 - 8 + col;
            float f0 = 0.f, f1 = 0.f, f2 = 0.f, f3 = 0.f;
            if (gh >= 0 && gh < NH && gw >= 0 && gw < NW) {
                const float* p = xln + ((size_t)(b * 64 + chunk * 16 + cg * 4) * NH + gh) * NW + gw;
                f0 = p[0]; f1 = p[HWp]; f2 = p[2 * HWp]; f3 = p[3 * HWp];
            }
            short4t sv = {f2bf(f0), f2bf(f1), f2bf(f2), f2bf(f3)};
            short* dst = tile + (cg >= 2 ? 9 * 144 * 8 : 0) + (r * 144 + col) * 8 + (cg & 1) * 4;
            *(short4t*)dst = sv;
        }
        __syncthreads();

        const short* wbase = WB + (size_t)((b * 4 + chunk) * 18) * 2048 + ln15 * 32 + g * 8;
        for (int tp = 0; tp < 18; ++tp) {
            int ta = 2 * tp, tb = ta + 1;
            int ma = ta / 9, k9a = ta % 9;
            int mb = tb / 9, k9b = tb % 9;
            int offA = ((4 + (ma + 1) * (k9a / 3 - 1)) * 144 + 8 + 2 * (ma + 1) * (k9a % 3 - 1)) * 8;
            int offB = ((4 + (mb + 1) * (k9b / 3 - 1)) * 144 + 8 + 2 * (mb + 1) * (k9b % 3 - 1)) * 8;
            int aoff = (tsel ? offB : offA) + laneelem + halfoff;
            const short* ap = tile + aoff;
            short8 a0 = *(const short8*)(ap);
            short8 a1 = *(const short8*)(ap + 128);
            short8 a2 = *(const short8*)(ap + 256);
            short8 a3 = *(const short8*)(ap + 384);
            const short* bp = wbase + (size_t)tp * 2048;
            short8 b0 = *(const short8*)(bp);
            short8 b1 = *(const short8*)(bp + 512);
            short8 b2 = *(const short8*)(bp + 1024);
            short8 b3 = *(const short8*)(bp + 1536);
            acc[0][0] = __builtin_amdgcn_mfma_f32_16x16x32_bf16(a0, b0, acc[0][0], 0, 0, 0);
            acc[0][1] = __builtin_amdgcn_mfma_f32_16x16x32_bf16(a0, b1, acc[0][1], 0, 0, 0);
            acc[0][2] = __builtin_amdgcn_mfma_f32_16x16x32_bf16(a0, b2, acc[0][2], 0, 0, 0);
            acc[0][3] = __builtin_amdgcn_mfma_f32_16x16x32_bf16(a0, b3, acc[0][3], 0, 0, 0);
            acc[1][0] = __builtin_amdgcn_mfma_f32_16x16x32_bf16(a1, b0, acc[1][0], 0, 0, 0);
            acc[1][1] = __builtin_amdgcn_mfma_f32_16x16x32_bf16(a1, b1, acc[1][1], 0, 0, 0);
            acc[1][2] = __builtin_amdgcn_mfma_f32_16x16x32_bf16(a1, b2, acc[1][2], 0, 0, 0);
            acc[1][3] = __builtin_amdgcn_mfma_f32_16x16x32_bf16(a1, b3, acc[1][3], 0, 0, 0);
            acc[2][0] = __builtin_amdgcn_mfma_f32_16x16x32_bf16(a2, b0, acc[2][0], 0, 0, 0);
            acc[2][1] = __builtin_amdgcn_mfma_f32_16x16x32_bf16(a2, b1, acc[2][1], 0, 0, 0);
            acc[2][2] = __builtin_amdgcn_mfma_f32_16x16x32_bf16(a2, b2, acc[2][2], 0, 0, 0);
            acc[2][3] = __builtin_amdgcn_mfma_f32_16x16x32_bf16(a2, b3, acc[2][3], 0, 0, 0);
            acc[3][0] = __builtin_amdgcn_mfma_f32_16x16x32_bf16(a3, b0, acc[3][0], 0, 0, 0);
            acc[3][1] = __builtin_amdgcn_mfma_f32_16x16x32_bf16(a3, b1, acc[3][1], 0, 0, 0);
            acc[3][2] = __builtin_amdgcn_mfma_f32_16x16x32_bf16(a3, b2, acc[3][2], 0, 0, 0);
            acc[3][3] = __builtin_amdgcn_mfma_f32_16x16x32_bf16(a3, b3, acc[3][3], 0, 0, 0);
        }
    }
    // epilogue: D row=(lane>>4)*4+j (px), col=lane&15 (co); store bf16 NHWC
#pragma unroll
    for (int mt = 0; mt < 4; ++mt) {
        int px = w0 + wave * 64 + mt * 16 + (lane >> 4) * 4;
#pragma unroll
        for (int j = 0; j < 4; ++j) {
            short* qp = Qs + ((size_t)(b * NH + h) * NW + px + j) * 64 + ln15;
            qp[0]  = f2bf(acc[mt][0][j]);
            qp[16] = f2bf(acc[mt][1][j]);
            qp[32] = f2bf(acc[mt][2][j]);
            qp[48] = f2bf(acc[mt][3][j]);
        }
    }
}

// ---------------------------------------------------------------------------
// 1x1 conv V = x @ w2^T + b2, output bf16 "NCHW w-permuted": per 64-w tile,
// VT[b][c][h][wt*64 + s] = V[wt*64 + u(s)][c],  u(s) = (s>>2) + 16*(s&3).
// ---------------------------------------------------------------------------
__global__ __launch_bounds__(256) void k_v(const float* __restrict__ x,
                                           const float* __restrict__ w2,
                                           const float* __restrict__ b2,
                                           short* __restrict__ VT) {
    int wt = blockIdx.x, h = blockIdx.y, b = blockIdx.z;
    int t = threadIdx.x, lane = t & 63, q = t >> 6;
    __shared__ float xs[64 * 68];    // [ci][px] then reused as [c][px]
    __shared__ float w2t[64 * 68];   // [ci][c]
    int w0 = wt * 64;
    const float* src = x + (size_t)(b * 64) * HWp + h * NW + w0;
    for (int idx = t; idx < 4096; idx += 256) {
        int ci = idx >> 6, col = idx & 63;
        xs[ci * 68 + col] = src[(size_t)ci * HWp + col];
    }
    for (int idx = t; idx < 4096; idx += 256) {
        int co = idx >> 6, ci = idx & 63;
        w2t[ci * 68 + co] = w2[co * 64 + ci];
    }
    __syncthreads();

    const int pl0 = (lane & 15) * 4;            // 4 px per thread
    const int c0 = q * 16 + (lane >> 4) * 4;    // 4 c per thread
    f32x4 a4[4];
#pragma unroll
    for (int cc = 0; cc < 4; ++cc) {
        float bb = b2[c0 + cc];
        a4[cc] = (f32x4){bb, bb, bb, bb};
    }
    for (int ci = 0; ci < 64; ++ci) {
        f32x4 xv = *(const f32x4*)(xs + ci * 68 + pl0);
        f32x4 wv = *(const f32x4*)(w2t + ci * 68 + c0);
        a4[0] += xv * wv[0];
        a4[1] += xv * wv[1];
        a4[2] += xv * wv[2];
        a4[3] += xv * wv[3];
    }
    __syncthreads();
#pragma unroll
    for (int cc = 0; cc < 4; ++cc)
        *(f32x4*)(xs + (c0 + cc) * 68 + pl0) = a4[cc];
    __syncthreads();
    {
        int s = t & 63, g2 = t >> 6;
        int u = (s >> 2) + 16 * (s & 3);
#pragma unroll
        for (int cc = 0; cc < 16; ++cc) {
            int ch = g2 * 16 + cc;
            VT[((size_t)(b * 64 + ch) * NH + h) * NW + w0 + s] = f2bf(xs[ch * 68 + u]);
        }
    }
}

// ---------------------------------------------------------------------------
// Fused cross-attention, flash-style, both QK^T and PV on MFMA.
// Grid (2, NH, NB), 128 thr = 2 waves. Wave owns 64 query rows.
// ---------------------------------------------------------------------------
__global__ __launch_bounds__(128, 2) void k_attn(const short* __restrict__ Qa,
                                                 const short* __restrict__ Qbp,
                                                 const short* __restrict__ VT,
                                                 const float* __restrict__ xres,
                                                 const float* __restrict__ scl,
                                                 float* __restrict__ out) {
    const int bx = blockIdx.x, h = blockIdx.y, b = blockIdx.z;
    const int t = threadIdx.x, lane = t & 63, wave = t >> 6;
    const int q = lane >> 4, c15 = lane & 15;
    __shared__ __align__(16) short PB[2][64 * 72];
    short* pb = PB[wave];

    const int wbase = bx * 128 + wave * 64;
    const short* qabase = Qa + ((size_t)(b * NH + h) * NW + wbase) * 64;
    const short* qbbase = Qbp + ((size_t)(b * NH + h) * NW) * 64;

    short8 afrag[4][2];
#pragma unroll
    for (int mt = 0; mt < 4; ++mt)
#pragma unroll
        for (int kk = 0; kk < 2; ++kk)
            afrag[mt][kk] = *(const short8*)(qabase + (mt * 16 + c15) * 64 + kk * 32 + q * 8);

    f32x4 osum[4][4];
#pragma unroll
    for (int mt = 0; mt < 4; ++mt)
#pragma unroll
        for (int nt = 0; nt < 4; ++nt) osum[mt][nt] = (f32x4){0.f, 0.f, 0.f, 0.f};
    float mrow[16], lrow[16];
#pragma unroll
    for (int i = 0; i < 16; ++i) { mrow[i] = -1e30f; lrow[i] = 0.f; }

    for (int vt = 0; vt < 4; ++vt) {
        f32x4 s[4][4];
#pragma unroll
        for (int mt = 0; mt < 4; ++mt)
#pragma unroll
            for (int nt = 0; nt < 4; ++nt) s[mt][nt] = (f32x4){0.f, 0.f, 0.f, 0.f};
#pragma unroll
        for (int kk = 0; kk < 2; ++kk) {
            short8 bq[4];
#pragma unroll
            for (int nt = 0; nt < 4; ++nt)
                bq[nt] = *(const short8*)(qbbase + (size_t)(vt * 64 + nt * 16 + c15) * 64 + kk * 32 + q * 8);
#pragma unroll
            for (int mt = 0; mt < 4; ++mt)
#pragma unroll
                for (int nt = 0; nt < 4; ++nt)
                    s[mt][nt] = __builtin_amdgcn_mfma_f32_16x16x32_bf16(afrag[mt][kk], bq[nt], s[mt][nt], 0, 0, 0);
        }
#pragma unroll
        for (int mt = 0; mt < 4; ++mt)
#pragma unroll
            for (int nt = 0; nt < 4; ++nt)
#pragma unroll
                for (int r = 0; r < 4; ++r) s[mt][nt][r] *= 0.125f;
        float al[16];
#pragma unroll
        for (int mt = 0; mt < 4; ++mt)
#pragma unroll
            for (int r = 0; r < 4; ++r) {
                float m0 = fmaxf(fmaxf(s[mt][0][r], s[mt][1][r]), fmaxf(s[mt][2][r], s[mt][3][r]));
#pragma unroll
                for (int msk = 1; msk < 16; msk <<= 1) m0 = fmaxf(m0, __shfl_xor(m0, msk, 64));
                int i = mt * 4 + r;
                float mn = fmaxf(mrow[i], m0);
                al[i] = __expf(mrow[i] - mn);
                mrow[i] = mn;
            }
#pragma unroll
        for (int mt = 0; mt < 4; ++mt)
#pragma unroll
            for (int r = 0; r < 4; ++r) {
                int i = mt * 4 + r;
                float m = mrow[i];
                float p0 = __expf(s[mt][0][r] - m);
                float p1 = __expf(s[mt][1][r] - m);
                float p2 = __expf(s[mt][2][r] - m);
                float p3 = __expf(s[mt][3][r] - m);
                short4t pk = {f2bf(p0), f2bf(p1), f2bf(p2), f2bf(p3)};
                *(short4t*)(pb + (mt * 16 + q * 4 + r) * 72 + c15 * 4) = pk;
                float lsv = (p0 + p1) + (p2 + p3);
#pragma unroll
                for (int msk = 1; msk < 16; msk <<= 1) lsv += __shfl_xor(lsv, msk, 64);
                lrow[i] = lrow[i] * al[i] + lsv;
            }
#pragma unroll
        for (int mt = 0; mt < 4; ++mt)
#pragma unroll
            for (int nt = 0; nt < 4; ++nt)
#pragma unroll
                for (int r = 0; r < 4; ++r) osum[mt][nt][r] *= al[mt * 4 + r];
#pragma unroll
        for (int kk = 0; kk < 2; ++kk) {
            short8 ap[4], bv[4];
#pragma unroll
            for (int mt = 0; mt < 4; ++mt)
                ap[mt] = *(const short8*)(pb + (mt * 16 + c15) * 72 + kk * 32 + q * 8);
#pragma unroll
            for (int nt = 0; nt < 4; ++nt)
                bv[nt] = *(const short8*)(VT + ((size_t)(b * 64 + nt * 16 + c15) * NH + h) * NW + vt * 64 + kk * 32 + q * 8);
#pragma unroll
            for (int mt = 0; mt < 4; ++mt)
#pragma unroll
                for (int nt = 0; nt < 4; ++nt)
                    osum[mt][nt] = __builtin_amdgcn_mfma_f32_16x16x32_bf16(ap[mt], bv[nt], osum[mt][nt], 0, 0, 0);
        }
    }
    float linv[16];
#pragma unroll
    for (int i = 0; i < 16; ++i) linv[i] = 1.f / lrow[i];
#pragma unroll
    for (int nt = 0; nt < 4; ++nt) {
        int c = nt * 16 + c15;
        float bv = scl[c];
        size_t pbase = ((size_t)(b * 64 + c) * NH + h) * NW + wbase;
#pragma unroll
        for (int mt = 0; mt < 4; ++mt)
#pragma unroll
            for (int r = 0; r < 4; ++r) {
                size_t o = pbase + mt * 16 + q * 4 + r;
                out[o] = xres[o] + osum[mt][nt][r] * linv[mt * 4 + r] * bv;
            }
    }
}

// ---------------------------------------------------------------------------
extern "C" void kernel_launch(void* const* d_in, const int* in_sizes, int n_in,
                              void* d_out, int out_size, void* d_ws, size_t ws_size,
                              hipStream_t stream) {
    const float* x_l   = (const float*)d_in[0];
    const float* x_r   = (const float*)d_in[1];
    const float* lnl_g = (const float*)d_in[2];
    const float* lnl_b = (const float*)d_in[3];
    const float* lnr_g = (const float*)d_in[4];
    const float* lnr_b = (const float*)d_in[5];
    const float* l_dw  = (const float*)d_in[6];
    const float* l_db  = (const float*)d_in[7];
    const float* l_c1w = (const float*)d_in[8];
    const float* l_c1b = (const float*)d_in[9];
    const float* l_pw  = (const float*)d_in[10];
    const float* r_dw  = (const float*)d_in[11];
    const float* r_db  = (const float*)d_in[12];
    const float* r_c1w = (const float*)d_in[13];
    const float* r_c1b = (const float*)d_in[14];
    const float* r_pw  = (const float*)d_in[15];
    const float* l2w   = (const float*)d_in[16];
    const float* l2b   = (const float*)d_in[17];
    const float* r2w   = (const float*)d_in[18];
    const float* r2b   = (const float*)d_in[19];
    const float* beta  = (const float*)d_in[20];
    const float* gamma = (const float*)d_in[21];
    float* out = (float*)d_out;

    constexpr size_t PLANE = (size_t)NB * NC * NH * NW;   // 6291456
    float* ws = (float*)d_ws;
    float* XLN = ws;                 ws += PLANE;
    short* QLs = (short*)ws;         ws += PLANE / 2;
    short* QRs = (short*)ws;         ws += PLANE / 2;
    short* VLs = (short*)ws;         ws += PLANE / 2;
    short* VRs = (short*)ws;         ws += PLANE / 2;
    short* WB  = (short*)ws;         ws += 294912;   // 589824 bf16
    float* Tb  = ws;                 ws += 9216;
    float* SW  = ws;                 ws += 1024;
    float* QB  = ws;                 ws += 256;
    float* Zb  = ws;                 ws += 256;

    dim3 blk(256);
    // --- left SKM ---
    k_ln    <<<dim3(NH, NB), blk, 0, stream>>>(x_l, lnl_g, lnl_b, XLN);
    k_rect  <<<dim3(NB * NC), blk, 0, stream>>>(XLN, Tb);
    k_z     <<<dim3(256), blk, 0, stream>>>(Tb, l_dw, l_db, Zb);
    k_sel2  <<<dim3(4), blk, 0, stream>>>(Zb, l_db, l_c1w, l_c1b, l_pw, SW, QB);
    k_fold  <<<dim3(2304), blk, 0, stream>>>(l_dw, SW, WB);
    k_convm <<<dim3(2, NH, NB), dim3(128), 0, stream>>>(XLN, WB, QB, QLs);
    k_v     <<<dim3(4, NH, NB), blk, 0, stream>>>(x_l, l2w, l2b, VLs);
    // --- right SKM ---
    k_ln    <<<dim3(NH, NB), blk, 0, stream>>>(x_r, lnr_g, lnr_b, XLN);
    k_rect  <<<dim3(NB * NC), blk, 0, stream>>>(XLN, Tb);
    k_z     <<<dim3(256), blk, 0, stream>>>(Tb, r_dw, r_db, Zb);
    k_sel2  <<<dim3(4), blk, 0, stream>>>(Zb, r_db, r_c1w, r_c1b, r_pw, SW, QB);
    k_fold  <<<dim3(2304), blk, 0, stream>>>(r_dw, SW, WB);
    k_convm <<<dim3(2, NH, NB), dim3(128), 0, stream>>>(XLN, WB, QB, QRs);
    k_v     <<<dim3(4, NH, NB), blk, 0, stream>>>(x_r, r2w, r2b, VRs);
    // --- fused cross attention (both directions) ---
    k_attn  <<<dim3(2, NH, NB), dim3(128), 0, stream>>>(QLs, QRs, VRs, x_l, beta, out);
    k_attn  <<<dim3(2, NH, NB), dim3(128), 0, stream>>>(QRs, QLs, VLs, x_r, gamma, out + PLANE);
}

// Round 6
// 449.350 us; speedup vs baseline: 2.3501x; 1.2068x over previous
//
#include <hip/hip_runtime.h>
#include <hip/hip_bf16.h>
#include <cstdint>

// Problem constants (B,C,H,W fixed by setup_inputs)
constexpr int NB = 4;
constexpr int NC = 64;
constexpr int NH = 96;
constexpr int NW = 256;
constexpr int HWp = NH * NW;          // 24576 pixels per plane
constexpr float EPS = 1e-6f;

typedef __attribute__((ext_vector_type(8))) short short8;
typedef __attribute__((ext_vector_type(4))) short short4t;
typedef __attribute__((ext_vector_type(4))) float f32x4;

static __device__ __forceinline__ short f2bf(float f) {
    __hip_bfloat16 h = __float2bfloat16(f);
    return *reinterpret_cast<short*>(&h);
}

// ---------------------------------------------------------------------------
// LayerNorm2d over channels at each (b,h,w). Block = one (b,h) row, 256 thr.
// Writes fp32 XLN (for k_rect) and bf16 XB[b][chunk][h][w][16ci] (for k_convm;
// 32B/px/chunk contiguous -> conflict-free b128 LDS staging downstream).
// ---------------------------------------------------------------------------
__global__ __launch_bounds__(256) void k_ln(const float* __restrict__ x,
                                            const float* __restrict__ g,
                                            const float* __restrict__ bta,
                                            float* __restrict__ out,
                                            short* __restrict__ XB) {
    int h = blockIdx.x, b = blockIdx.y, w = threadIdx.x;
    const float* xp = x + ((size_t)b * NC * NH + h) * NW + w;
    float v[64];
    float s = 0.f, sq = 0.f;
#pragma unroll
    for (int c = 0; c < 64; ++c) {
        float t = xp[(size_t)c * HWp];
        v[c] = t; s += t; sq += t * t;
    }
    float mu = s * (1.f / 64.f);
    float var = sq * (1.f / 64.f) - mu * mu;
    float rs = rsqrtf(var + EPS);
    float* op = out + ((size_t)b * NC * NH + h) * NW + w;
#pragma unroll
    for (int c = 0; c < 64; ++c) {
        v[c] = (v[c] - mu) * rs * g[c] + bta[c];
        op[(size_t)c * HWp] = v[c];
    }
#pragma unroll
    for (int chunk = 0; chunk < 4; ++chunk) {
        short8 s0, s1;
#pragma unroll
        for (int j = 0; j < 8; ++j) {
            s0[j] = f2bf(v[chunk * 16 + j]);
            s1[j] = f2bf(v[chunk * 16 + 8 + j]);
        }
        short* xb = XB + (((size_t)(b * 4 + chunk) * NH + h) * NW + w) * 16;
        *(short8*)xb = s0;
        *(short8*)(xb + 8) = s1;
    }
}

// ---------------------------------------------------------------------------
// Rectangle sums for the SKM global pool (D never materialized).
// T layout: [b][m][ci][9]
// ---------------------------------------------------------------------------
__global__ __launch_bounds__(256) void k_rect(const float* __restrict__ xln,
                                              float* __restrict__ T) {
    int bci = blockIdx.x;
    int b = bci >> 6, ci = bci & 63;
    int t = threadIdx.x, lane = t & 63, wv = t >> 6;
    __shared__ float rp[NH][9];
    const float* base = xln + (size_t)bci * HWp;
    for (int r = wv; r < NH; r += 4) {
        float4 vv = *(const float4*)(base + r * NW + lane * 4);
        float a = vv.x + vv.y, bb = vv.z + vv.w;
        float s4 = a + bb;
        float full = s4;
#pragma unroll
        for (int o = 32; o; o >>= 1) full += __shfl_xor(full, o, 64);
        float l0a = __shfl(a, 0, 64),  l0s = __shfl(s4, 0, 64);
        float l1a = __shfl(a, 1, 64),  l1s = __shfl(s4, 1, 64);
        float r63b = __shfl(bb, 63, 64), r63s = __shfl(s4, 63, 64);
        float r62b = __shfl(bb, 62, 64), r62s = __shfl(s4, 62, 64);
        if (lane == 0) {
            rp[r][0] = full;
            rp[r][1] = l0a;  rp[r][2] = l0s;  rp[r][3] = l0s + l1a;  rp[r][4] = l0s + l1s;
            rp[r][5] = r63b; rp[r][6] = r63s; rp[r][7] = r63s + r62b; rp[r][8] = r63s + r62s;
        }
    }
    __syncthreads();
    if (t < 36) {
        int m = t / 9, kh = (t % 9) / 3, kw = t % 3;
        int d = 2 * (m + 1);
        int r0 = (kh == 2) ? d : 0;
        int r1 = (kh == 0) ? NH - d : NH;
        float s = 0.f;
        for (int r = r0; r < r1; ++r) {
            float rowv = rp[r][0];
            if (kw == 0) rowv -= rp[r][5 + m];
            else if (kw == 2) rowv -= rp[r][1 + m];
            s += rowv;
        }
        T[(((b * 4 + m) * 64) + ci) * 9 + kh * 3 + kw] = s;
    }
}

// ---------------------------------------------------------------------------
// Z[b,c] = (1/HW) * sum_m dot(dw[m,c,:], T[b,m,:]) + sum_m db[m,c]
// ---------------------------------------------------------------------------
__global__ __launch_bounds__(256) void k_z(const float* __restrict__ T,
                                           const float* __restrict__ dw,
                                           const float* __restrict__ db,
                                           float* __restrict__ Z) {
    int bc = blockIdx.x;
    int b = bc >> 6, c = bc & 63;
    int t = threadIdx.x, lane = t & 63, m = t >> 6;
    const float* wp = dw + (size_t)(m * 64 + c) * 576;
    const float* tp = T + (size_t)(b * 4 + m) * 576;
    float s = 0.f;
    for (int j = lane; j < 576; j += 64) s += wp[j] * tp[j];
#pragma unroll
    for (int o = 32; o; o >>= 1) s += __shfl_xor(s, o, 64);
    __shared__ float red[4];
    if (lane == 0) red[m] = s;
    __syncthreads();
    if (t == 0) {
        float z = (red[0] + red[1]) + (red[2] + red[3]);
        float bias = db[c] + db[64 + c] + db[128 + c] + db[192 + c];
        Z[bc] = z * (1.f / (float)HWp) + bias;
    }
}

// ---------------------------------------------------------------------------
// Selection MLP tail: S=relu(Z@c1w^T+c1b); P=S@pw; softmax over c per m.
// ---------------------------------------------------------------------------
__global__ __launch_bounds__(256) void k_sel2(const float* __restrict__ Z,
                                              const float* __restrict__ db,
                                              const float* __restrict__ c1w,
                                              const float* __restrict__ c1b,
                                              const float* __restrict__ pw,
                                              float* __restrict__ Sw,
                                              float* __restrict__ Qb) {
    int b = blockIdx.x;
    int t = threadIdx.x, lane = t & 63, wv = t >> 6;
    __shared__ float zs[64], ss[128], sw[256];
    __shared__ float cw[128 * 64];
    if (t < 64) zs[t] = Z[b * 64 + t];
    for (int i = t; i < 8192; i += 256) cw[i] = c1w[i];
    __syncthreads();
    if (t < 128) {
        float s = c1b[t];
        const float* wrow = cw + t * 64;
        for (int c = 0; c < 64; ++c) s += zs[c] * wrow[c];
        ss[t] = fmaxf(s, 0.f);
    }
    __syncthreads();
    float p = 0.f;
    for (int j = 0; j < 128; ++j) p += ss[j] * pw[j * 256 + t];
    float mx = p;
#pragma unroll
    for (int o = 32; o; o >>= 1) mx = fmaxf(mx, __shfl_xor(mx, o, 64));
    float e = __expf(p - mx);
    float sum = e;
#pragma unroll
    for (int o = 32; o; o >>= 1) sum += __shfl_xor(sum, o, 64);
    float swv = e / sum;
    Sw[(b * 4 + wv) * 64 + lane] = swv;
    sw[wv * 64 + lane] = swv;
    __syncthreads();
    if (t < 64) {
        float qb = sw[t] * db[t] + sw[64 + t] * db[64 + t]
                 + sw[128 + t] * db[128 + t] + sw[192 + t] * db[192 + t];
        Qb[b * 64 + t] = qb;
    }
}

// ---------------------------------------------------------------------------
// Fold Sw into conv weights, bf16, pre-swizzled to MFMA B-fragment order:
// WB[b][chunk(4)][tpair(18)][co(64)][k32], k = tpl*16 + cil.
// ---------------------------------------------------------------------------
__global__ __launch_bounds__(256) void k_fold(const float* __restrict__ dw,
                                              const float* __restrict__ Sw,
                                              short* __restrict__ WB) {
    int idx = blockIdx.x * 256 + threadIdx.x;   // 589824 total
    int kk = idx & 31;
    int co = (idx >> 5) & 63;
    int rest = idx >> 11;            // [0,288)
    int tpair = rest % 18;
    int bc = rest / 18;              // [0,16)
    int chunk = bc & 3, b = bc >> 2;
    int tpl = kk >> 4, cil = kk & 15;
    int tap = 2 * tpair + tpl;
    int m = tap / 9, k9 = tap % 9;
    int ci = chunk * 16 + cil;
    float val = Sw[(b * 4 + m) * 64 + co] * dw[(size_t)((m * 64 + co) * 64 + ci) * 9 + k9];
    WB[idx] = f2bf(val);
}

// ---------------------------------------------------------------------------
// MFMA implicit-GEMM fused 4-dilation conv -> Q (bf16 NHWC).
// R5: input is pre-converted bf16 XB[b][chunk][h][w][16]; staging is 2x16B
// global load + 2x ds_write_b128 at 16B lane stride (conflict-free), replacing
// R4's 4 scalar fp32 loads + cvt per slot (995K bank conflicts, VALU-bound).
// ---------------------------------------------------------------------------
__global__ __launch_bounds__(128) void k_convm(const short* __restrict__ XB,
                                               const short* __restrict__ WB,
                                               const float* __restrict__ Qb,
                                               short* __restrict__ Qs) {
    const int wt = blockIdx.x, h = blockIdx.y, b = blockIdx.z;
    const int t = threadIdx.x;
    const int lane = t & 63, wave = t >> 6;
    const int g = lane >> 4, ln15 = lane & 15;
    __shared__ short tile[2 * 9 * 144 * 8];   // [half][r][col][ci8]

    f32x4 acc[4][4];
    {
        float qb[4];
#pragma unroll
        for (int nt = 0; nt < 4; ++nt) qb[nt] = Qb[b * 64 + nt * 16 + ln15];
#pragma unroll
        for (int mt = 0; mt < 4; ++mt)
#pragma unroll
            for (int nt = 0; nt < 4; ++nt)
                acc[mt][nt] = (f32x4){qb[nt], qb[nt], qb[nt], qb[nt]};
    }
    const int w0 = wt * 128;
    const int laneelem = (wave * 64 + ln15) * 8;
    const int halfoff = (g & 1) * (9 * 144 * 8);
    const int tsel = g >> 1;

    for (int chunk = 0; chunk < 4; ++chunk) {
        __syncthreads();
        const short* src = XB + (size_t)(b * 4 + chunk) * NH * NW * 16;
        for (int slot = t; slot < 9 * 144; slot += 128) {
            int r = slot / 144, col = slot % 144;
            int gh = h + 2 * r - 8;
            int gw = w0 - 8 + col;
            short8 v0 = {0, 0, 0, 0, 0, 0, 0, 0};
            short8 v1 = {0, 0, 0, 0, 0, 0, 0, 0};
            if (gh >= 0 && gh < NH && gw >= 0 && gw < NW) {
                const short* p = src + ((size_t)gh * NW + gw) * 16;
                v0 = *(const short8*)p;
                v1 = *(const short8*)(p + 8);
            }
            *(short8*)(tile + slot * 8) = v0;                 // half 0 (ci 0..7)
            *(short8*)(tile + (9 * 144 + slot) * 8) = v1;     // half 1 (ci 8..15)
        }
        __syncthreads();

        const short* wbase = WB + (size_t)((b * 4 + chunk) * 18) * 2048 + ln15 * 32 + g * 8;
        for (int tp = 0; tp < 18; ++tp) {
            int ta = 2 * tp, tb = ta + 1;
            int ma = ta / 9, k9a = ta % 9;
            int mb = tb / 9, k9b = tb % 9;
            int offA = ((4 + (ma + 1) * (k9a / 3 - 1)) * 144 + 8 + 2 * (ma + 1) * (k9a % 3 - 1)) * 8;
            int offB = ((4 + (mb + 1) * (k9b / 3 - 1)) * 144 + 8 + 2 * (mb + 1) * (k9b % 3 - 1)) * 8;
            int aoff = (tsel ? offB : offA) + laneelem + halfoff;
            const short* ap = tile + aoff;
            short8 a0 = *(const short8*)(ap);
            short8 a1 = *(const short8*)(ap + 128);
            short8 a2 = *(const short8*)(ap + 256);
            short8 a3 = *(const short8*)(ap + 384);
            const short* bp = wbase + (size_t)tp * 2048;
            short8 b0 = *(const short8*)(bp);
            short8 b1 = *(const short8*)(bp + 512);
            short8 b2 = *(const short8*)(bp + 1024);
            short8 b3 = *(const short8*)(bp + 1536);
            acc[0][0] = __builtin_amdgcn_mfma_f32_16x16x32_bf16(a0, b0, acc[0][0], 0, 0, 0);
            acc[0][1] = __builtin_amdgcn_mfma_f32_16x16x32_bf16(a0, b1, acc[0][1], 0, 0, 0);
            acc[0][2] = __builtin_amdgcn_mfma_f32_16x16x32_bf16(a0, b2, acc[0][2], 0, 0, 0);
            acc[0][3] = __builtin_amdgcn_mfma_f32_16x16x32_bf16(a0, b3, acc[0][3], 0, 0, 0);
            acc[1][0] = __builtin_amdgcn_mfma_f32_16x16x32_bf16(a1, b0, acc[1][0], 0, 0, 0);
            acc[1][1] = __builtin_amdgcn_mfma_f32_16x16x32_bf16(a1, b1, acc[1][1], 0, 0, 0);
            acc[1][2] = __builtin_amdgcn_mfma_f32_16x16x32_bf16(a1, b2, acc[1][2], 0, 0, 0);
            acc[1][3] = __builtin_amdgcn_mfma_f32_16x16x32_bf16(a1, b3, acc[1][3], 0, 0, 0);
            acc[2][0] = __builtin_amdgcn_mfma_f32_16x16x32_bf16(a2, b0, acc[2][0], 0, 0, 0);
            acc[2][1] = __builtin_amdgcn_mfma_f32_16x16x32_bf16(a2, b1, acc[2][1], 0, 0, 0);
            acc[2][2] = __builtin_amdgcn_mfma_f32_16x16x32_bf16(a2, b2, acc[2][2], 0, 0, 0);
            acc[2][3] = __builtin_amdgcn_mfma_f32_16x16x32_bf16(a2, b3, acc[2][3], 0, 0, 0);
            acc[3][0] = __builtin_amdgcn_mfma_f32_16x16x32_bf16(a3, b0, acc[3][0], 0, 0, 0);
            acc[3][1] = __builtin_amdgcn_mfma_f32_16x16x32_bf16(a3, b1, acc[3][1], 0, 0, 0);
            acc[3][2] = __builtin_amdgcn_mfma_f32_16x16x32_bf16(a3, b2, acc[3][2], 0, 0, 0);
            acc[3][3] = __builtin_amdgcn_mfma_f32_16x16x32_bf16(a3, b3, acc[3][3], 0, 0, 0);
        }
    }
    // epilogue: D row=(lane>>4)*4+j (px), col=lane&15 (co); store bf16 NHWC
#pragma unroll
    for (int mt = 0; mt < 4; ++mt) {
        int px = w0 + wave * 64 + mt * 16 + (lane >> 4) * 4;
#pragma unroll
        for (int j = 0; j < 4; ++j) {
            short* qp = Qs + ((size_t)(b * NH + h) * NW + px + j) * 64 + ln15;
            qp[0]  = f2bf(acc[mt][0][j]);
            qp[16] = f2bf(acc[mt][1][j]);
            qp[32] = f2bf(acc[mt][2][j]);
            qp[48] = f2bf(acc[mt][3][j]);
        }
    }
}

// ---------------------------------------------------------------------------
// 1x1 conv V = x @ w2^T + b2, output bf16 "NCHW w-permuted": per 64-w tile,
// VT[b][c][h][wt*64 + s] = V[wt*64 + u(s)][c],  u(s) = (s>>2) + 16*(s&3).
// ---------------------------------------------------------------------------
__global__ __launch_bounds__(256) void k_v(const float* __restrict__ x,
                                           const float* __restrict__ w2,
                                           const float* __restrict__ b2,
                                           short* __restrict__ VT) {
    int wt = blockIdx.x, h = blockIdx.y, b = blockIdx.z;
    int t = threadIdx.x, lane = t & 63, q = t >> 6;
    __shared__ float xs[64 * 68];    // [ci][px] then reused as [c][px]
    __shared__ float w2t[64 * 68];   // [ci][c]
    int w0 = wt * 64;
    const float* src = x + (size_t)(b * 64) * HWp + h * NW + w0;
    for (int idx = t; idx < 4096; idx += 256) {
        int ci = idx >> 6, col = idx & 63;
        xs[ci * 68 + col] = src[(size_t)ci * HWp + col];
    }
    for (int idx = t; idx < 4096; idx += 256) {
        int co = idx >> 6, ci = idx & 63;
        w2t[ci * 68 + co] = w2[co * 64 + ci];
    }
    __syncthreads();

    const int pl0 = (lane & 15) * 4;            // 4 px per thread
    const int c0 = q * 16 + (lane >> 4) * 4;    // 4 c per thread
    f32x4 a4[4];
#pragma unroll
    for (int cc = 0; cc < 4; ++cc) {
        float bb = b2[c0 + cc];
        a4[cc] = (f32x4){bb, bb, bb, bb};
    }
    for (int ci = 0; ci < 64; ++ci) {
        f32x4 xv = *(const f32x4*)(xs + ci * 68 + pl0);
        f32x4 wv = *(const f32x4*)(w2t + ci * 68 + c0);
        a4[0] += xv * wv[0];
        a4[1] += xv * wv[1];
        a4[2] += xv * wv[2];
        a4[3] += xv * wv[3];
    }
    __syncthreads();
#pragma unroll
    for (int cc = 0; cc < 4; ++cc)
        *(f32x4*)(xs + (c0 + cc) * 68 + pl0) = a4[cc];
    __syncthreads();
    {
        int s = t & 63, g2 = t >> 6;
        int u = (s >> 2) + 16 * (s & 3);
#pragma unroll
        for (int cc = 0; cc < 16; ++cc) {
            int ch = g2 * 16 + cc;
            VT[((size_t)(b * 64 + ch) * NH + h) * NW + w0 + s] = f2bf(xs[ch * 68 + u]);
        }
    }
}

// ---------------------------------------------------------------------------
// Fused cross-attention, flash-style, both QK^T and PV on MFMA.
// Grid (2, NH, NB), 128 thr = 2 waves. Wave owns 64 query rows.
// ---------------------------------------------------------------------------
__global__ __launch_bounds__(128, 2) void k_attn(const short* __restrict__ Qa,
                                                 const short* __restrict__ Qbp,
                                                 const short* __restrict__ VT,
                                                 const float* __restrict__ xres,
                                                 const float* __restrict__ scl,
                                                 float* __restrict__ out) {
    const int bx = blockIdx.x, h = blockIdx.y, b = blockIdx.z;
    const int t = threadIdx.x, lane = t & 63, wave = t >> 6;
    const int q = lane >> 4, c15 = lane & 15;
    __shared__ __align__(16) short PB[2][64 * 72];
    short* pb = PB[wave];

    const int wbase = bx * 128 + wave * 64;
    const short* qabase = Qa + ((size_t)(b * NH + h) * NW + wbase) * 64;
    const short* qbbase = Qbp + ((size_t)(b * NH + h) * NW) * 64;

    short8 afrag[4][2];
#pragma unroll
    for (int mt = 0; mt < 4; ++mt)
#pragma unroll
        for (int kk = 0; kk < 2; ++kk)
            afrag[mt][kk] = *(const short8*)(qabase + (mt * 16 + c15) * 64 + kk * 32 + q * 8);

    f32x4 osum[4][4];
#pragma unroll
    for (int mt = 0; mt < 4; ++mt)
#pragma unroll
        for (int nt = 0; nt < 4; ++nt) osum[mt][nt] = (f32x4){0.f, 0.f, 0.f, 0.f};
    float mrow[16], lrow[16];
#pragma unroll
    for (int i = 0; i < 16; ++i) { mrow[i] = -1e30f; lrow[i] = 0.f; }

    for (int vt = 0; vt < 4; ++vt) {
        f32x4 s[4][4];
#pragma unroll
        for (int mt = 0; mt < 4; ++mt)
#pragma unroll
            for (int nt = 0; nt < 4; ++nt) s[mt][nt] = (f32x4){0.f, 0.f, 0.f, 0.f};
#pragma unroll
        for (int kk = 0; kk < 2; ++kk) {
            short8 bq[4];
#pragma unroll
            for (int nt = 0; nt < 4; ++nt)
                bq[nt] = *(const short8*)(qbbase + (size_t)(vt * 64 + nt * 16 + c15) * 64 + kk * 32 + q * 8);
#pragma unroll
            for (int mt = 0; mt < 4; ++mt)
#pragma unroll
                for (int nt = 0; nt < 4; ++nt)
                    s[mt][nt] = __builtin_amdgcn_mfma_f32_16x16x32_bf16(afrag[mt][kk], bq[nt], s[mt][nt], 0, 0, 0);
        }
#pragma unroll
        for (int mt = 0; mt < 4; ++mt)
#pragma unroll
            for (int nt = 0; nt < 4; ++nt)
#pragma unroll
                for (int r = 0; r < 4; ++r) s[mt][nt][r] *= 0.125f;
        float al[16];
#pragma unroll
        for (int mt = 0; mt < 4; ++mt)
#pragma unroll
            for (int r = 0; r < 4; ++r) {
                float m0 = fmaxf(fmaxf(s[mt][0][r], s[mt][1][r]), fmaxf(s[mt][2][r], s[mt][3][r]));
#pragma unroll
                for (int msk = 1; msk < 16; msk <<= 1) m0 = fmaxf(m0, __shfl_xor(m0, msk, 64));
                int i = mt * 4 + r;
                float mn = fmaxf(mrow[i], m0);
                al[i] = __expf(mrow[i] - mn);
                mrow[i] = mn;
            }
#pragma unroll
        for (int mt = 0; mt < 4; ++mt)
#pragma unroll
            for (int r = 0; r < 4; ++r) {
                int i = mt * 4 + r;
                float m = mrow[i];
                float p0 = __expf(s[mt][0][r] - m);
                float p1 = __expf(s[mt][1][r] - m);
                float p2 = __expf(s[mt][2][r] - m);
                float p3 = __expf(s[mt][3][r] - m);
                short4t pk = {f2bf(p0), f2bf(p1), f2bf(p2), f2bf(p3)};
                *(short4t*)(pb + (mt * 16 + q * 4 + r) * 72 + c15 * 4) = pk;
                float lsv = (p0 + p1) + (p2 + p3);
#pragma unroll
                for (int msk = 1; msk < 16; msk <<= 1) lsv += __shfl_xor(lsv, msk, 64);
                lrow[i] = lrow[i] * al[i] + lsv;
            }
#pragma unroll
        for (int mt = 0; mt < 4; ++mt)
#pragma unroll
            for (int nt = 0; nt < 4; ++nt)
#pragma unroll
                for (int r = 0; r < 4; ++r) osum[mt][nt][r] *= al[mt * 4 + r];
#pragma unroll
        for (int kk = 0; kk < 2; ++kk) {
            short8 ap[4], bv[4];
#pragma unroll
            for (int mt = 0; mt < 4; ++mt)
                ap[mt] = *(const short8*)(pb + (mt * 16 + c15) * 72 + kk * 32 + q * 8);
#pragma unroll
            for (int nt = 0; nt < 4; ++nt)
                bv[nt] = *(const short8*)(VT + ((size_t)(b * 64 + nt * 16 + c15) * NH + h) * NW + vt * 64 + kk * 32 + q * 8);
#pragma unroll
            for (int mt = 0; mt < 4; ++mt)
#pragma unroll
                for (int nt = 0; nt < 4; ++nt)
                    osum[mt][nt] = __builtin_amdgcn_mfma_f32_16x16x32_bf16(ap[mt], bv[nt], osum[mt][nt], 0, 0, 0);
        }
    }
    float linv[16];
#pragma unroll
    for (int i = 0; i < 16; ++i) linv[i] = 1.f / lrow[i];
#pragma unroll
    for (int nt = 0; nt < 4; ++nt) {
        int c = nt * 16 + c15;
        float bv = scl[c];
        size_t pbase = ((size_t)(b * 64 + c) * NH + h) * NW + wbase;
#pragma unroll
        for (int mt = 0; mt < 4; ++mt)
#pragma unroll
            for (int r = 0; r < 4; ++r) {
                size_t o = pbase + mt * 16 + q * 4 + r;
                out[o] = xres[o] + osum[mt][nt][r] * linv[mt * 4 + r] * bv;
            }
    }
}

// ---------------------------------------------------------------------------
extern "C" void kernel_launch(void* const* d_in, const int* in_sizes, int n_in,
                              void* d_out, int out_size, void* d_ws, size_t ws_size,
                              hipStream_t stream) {
    const float* x_l   = (const float*)d_in[0];
    const float* x_r   = (const float*)d_in[1];
    const float* lnl_g = (const float*)d_in[2];
    const float* lnl_b = (const float*)d_in[3];
    const float* lnr_g = (const float*)d_in[4];
    const float* lnr_b = (const float*)d_in[5];
    const float* l_dw  = (const float*)d_in[6];
    const float* l_db  = (const float*)d_in[7];
    const float* l_c1w = (const float*)d_in[8];
    const float* l_c1b = (const float*)d_in[9];
    const float* l_pw  = (const float*)d_in[10];
    const float* r_dw  = (const float*)d_in[11];
    const float* r_db  = (const float*)d_in[12];
    const float* r_c1w = (const float*)d_in[13];
    const float* r_c1b = (const float*)d_in[14];
    const float* r_pw  = (const float*)d_in[15];
    const float* l2w   = (const float*)d_in[16];
    const float* l2b   = (const float*)d_in[17];
    const float* r2w   = (const float*)d_in[18];
    const float* r2b   = (const float*)d_in[19];
    const float* beta  = (const float*)d_in[20];
    const float* gamma = (const float*)d_in[21];
    float* out = (float*)d_out;

    constexpr size_t PLANE = (size_t)NB * NC * NH * NW;   // 6291456
    float* ws = (float*)d_ws;
    float* XLN = ws;                 ws += PLANE;
    short* XB  = (short*)ws;         ws += PLANE / 2;     // bf16 [b][chunk][h][w][16]
    short* QLs = (short*)ws;         ws += PLANE / 2;
    short* QRs = (short*)ws;         ws += PLANE / 2;
    short* VLs = (short*)ws;         ws += PLANE / 2;
    short* VRs = (short*)ws;         ws += PLANE / 2;
    short* WB  = (short*)ws;         ws += 294912;   // 589824 bf16
    float* Tb  = ws;                 ws += 9216;
    float* SW  = ws;                 ws += 1024;
    float* QB  = ws;                 ws += 256;
    float* Zb  = ws;                 ws += 256;

    dim3 blk(256);
    // --- left SKM ---
    k_ln    <<<dim3(NH, NB), blk, 0, stream>>>(x_l, lnl_g, lnl_b, XLN, XB);
    k_rect  <<<dim3(NB * NC), blk, 0, stream>>>(XLN, Tb);
    k_z     <<<dim3(256), blk, 0, stream>>>(Tb, l_dw, l_db, Zb);
    k_sel2  <<<dim3(4), blk, 0, stream>>>(Zb, l_db, l_c1w, l_c1b, l_pw, SW, QB);
    k_fold  <<<dim3(2304), blk, 0, stream>>>(l_dw, SW, WB);
    k_convm <<<dim3(2, NH, NB), dim3(128), 0, stream>>>(XB, WB, QB, QLs);
    k_v     <<<dim3(4, NH, NB), blk, 0, stream>>>(x_l, l2w, l2b, VLs);
    // --- right SKM ---
    k_ln    <<<dim3(NH, NB), blk, 0, stream>>>(x_r, lnr_g, lnr_b, XLN, XB);
    k_rect  <<<dim3(NB * NC), blk, 0, stream>>>(XLN, Tb);
    k_z     <<<dim3(256), blk, 0, stream>>>(Tb, r_dw, r_db, Zb);
    k_sel2  <<<dim3(4), blk, 0, stream>>>(Zb, r_db, r_c1w, r_c1b, r_pw, SW, QB);
    k_fold  <<<dim3(2304), blk, 0, stream>>>(r_dw, SW, WB);
    k_convm <<<dim3(2, NH, NB), dim3(128), 0, stream>>>(XB, WB, QB, QRs);
    k_v     <<<dim3(4, NH, NB), blk, 0, stream>>>(x_r, r2w, r2b, VRs);
    // --- fused cross attention (both directions) ---
    k_attn  <<<dim3(2, NH, NB), dim3(128), 0, stream>>>(QLs, QRs, VRs, x_l, beta, out);
    k_attn  <<<dim3(2, NH, NB), dim3(128), 0, stream>>>(QRs, QLs, VLs, x_r, gamma, out + PLANE);
}